// Round 2
// baseline (942.994 us; speedup 1.0000x reference)
//
#include <hip/hip_runtime.h>
#include <stdint.h>

typedef unsigned short u16;
typedef unsigned int u32;
typedef __bf16 bf16_t;
typedef bf16_t bf16x8 __attribute__((ext_vector_type(8)));
typedef float f32x4 __attribute__((ext_vector_type(4)));

#define DEV static __device__ __forceinline__

DEV float bf2f(u16 a) {
  union { u32 u; float f; } c; c.u = ((u32)a) << 16; return c.f;
}
DEV u16 f2bf(float f) {
  union { float f; u32 u; } c; c.f = f;
  return (u16)((c.u + 0x7FFFu + ((c.u >> 16) & 1u)) >> 16);
}
DEV f32x4 mfma16(bf16x8 a, bf16x8 b, f32x4 c) {
  return __builtin_amdgcn_mfma_f32_16x16x32_bf16(a, b, c, 0, 0, 0);
}
DEV float wave_sum(float v) {
#pragma unroll
  for (int off = 32; off > 0; off >>= 1) v += __shfl_xor(v, off, 64);
  return v;
}
DEV float sum16(float v) {
  v += __shfl_xor(v, 1, 64);
  v += __shfl_xor(v, 2, 64);
  v += __shfl_xor(v, 4, 64);
  v += __shfl_xor(v, 8, 64);
  return v;
}

// ---------------------------------------------------------------------------
// INIT: g-scaled [Wk;Wv] -> bf16, ck/dk correction vectors, slots copy,
// bf16 conversion of Wq / w_ih / w_hh / W1 / W2. All inputs fp32.
// ---------------------------------------------------------------------------
__global__ void __launch_bounds__(256) init_prep(
    const float* __restrict__ Wk, const float* __restrict__ Wv,
    const float* __restrict__ gfeat, const float* __restrict__ bfeat,
    const float* __restrict__ slots_init,
    const float* __restrict__ Wq, const float* __restrict__ w_ih,
    const float* __restrict__ w_hh, const float* __restrict__ W1,
    const float* __restrict__ W2,
    u16* __restrict__ wkvp, float* __restrict__ ckv, float* __restrict__ dkv,
    float* __restrict__ slots,
    u16* __restrict__ wqb, u16* __restrict__ wihb, u16* __restrict__ whhb,
    u16* __restrict__ w1b, u16* __restrict__ w2b) {
  const int blk = blockIdx.x;
  const int tid = threadIdx.x;
  if (blk < 128) {
    const int o = blk * 4 + (tid >> 6);
    const int lane = tid & 63;
    const int d = lane * 4;
    const float* wrow = (o < 256) ? (Wk + (size_t)o * 256) : (Wv + (size_t)(o - 256) * 256);
    float4 w4 = *(const float4*)(wrow + d);
    float4 g4 = *(const float4*)(gfeat + d);
    float4 b4 = *(const float4*)(bfeat + d);
    float w[4] = {w4.x, w4.y, w4.z, w4.w};
    float g[4] = {g4.x, g4.y, g4.z, g4.w};
    float b[4] = {b4.x, b4.y, b4.z, b4.w};
    float cs = 0.f, ds = 0.f;
    u16 outp[4];
#pragma unroll
    for (int j = 0; j < 4; j++) {
      float wg = w[j] * g[j];
      cs += wg;
      ds += b[j] * w[j];
      outp[j] = f2bf(wg);
    }
    *(ushort4*)(wkvp + (size_t)o * 256 + d) = make_ushort4(outp[0], outp[1], outp[2], outp[3]);
    cs = wave_sum(cs);
    ds = wave_sum(ds);
    if (lane == 0) { ckv[o] = cs; dkv[o] = ds; }
  } else if (blk < 256) {
    const int idx = (blk - 128) * 1024 + tid * 4;
    *(float4*)(slots + idx) = *(const float4*)(slots_init + idx);
  } else {
    const int i = (blk - 256) * 1024 + tid * 4;
    const float* src; u16* dst; int off;
    if (i < 65536)       { src = Wq;   dst = wqb;  off = i; }
    else if (i < 262144) { src = w_ih; dst = wihb; off = i - 65536; }
    else if (i < 458752) { src = w_hh; dst = whhb; off = i - 262144; }
    else if (i < 720896) { src = W1;   dst = w1b;  off = i - 458752; }
    else                 { src = W2;   dst = w2b;  off = i - 720896; }
    float4 v = *(const float4*)(src + off);
    *(ushort4*)(dst + off) = make_ushort4(f2bf(v.x), f2bf(v.y), f2bf(v.z), f2bf(v.w));
  }
}

// ---------------------------------------------------------------------------
// GEMM1: single-pass A. Each block: 128-row M-tile staged ONCE (fp32->bf16,
// LN stats fused), then oc-loop over all 512 outputs. B (wkvp, 256 KB) read
// directly from global (L2-resident) -> no Bsm, no per-k barriers.
// k stored [b][n][d], v stored transposed [b][d][n]. LN folded in epilogue.
// ---------------------------------------------------------------------------
__global__ void __launch_bounds__(256, 2) gemm_kv(
    const float* __restrict__ feat, const u16* __restrict__ wkvp,
    const float* __restrict__ ckv, const float* __restrict__ dkv,
    u16* __restrict__ kbuf, u16* __restrict__ vtbuf) {
  __shared__ u16 Asm[128 * 256];  // 64 KB, 16B-chunk swizzled
  __shared__ float mus[128];
  __shared__ float rss[128];
  const int tid = threadIdx.x;
  const int lane = tid & 63;
  const int wv = tid >> 6;
  const int cl = lane & 15;
  const int rq = lane >> 4;
  const int M0 = blockIdx.x * 128;
  const int wm = (wv & 1) * 64;
  const int wn = (wv >> 1) * 64;

  // ---- A staging (once) + fused LN stats ----
#pragma unroll 4
  for (int i = 0; i < 16; i++) {
    const int gr = i * 256 + tid;
    const int m = gr >> 5;   // row 0..127 (32 consecutive threads per row)
    const int kc = gr & 31;  // 16B chunk within row
    const float* fp = feat + (size_t)(M0 + m) * 256 + kc * 8;
    float4 a0 = *(const float4*)fp;
    float4 a1 = *(const float4*)(fp + 4);
    float t1 = a0.x + a0.y + a0.z + a0.w + a1.x + a1.y + a1.z + a1.w;
    float t2 = a0.x * a0.x + a0.y * a0.y + a0.z * a0.z + a0.w * a0.w +
               a1.x * a1.x + a1.y * a1.y + a1.z * a1.z + a1.w * a1.w;
    t1 += __shfl_xor(t1, 1, 64);  t2 += __shfl_xor(t2, 1, 64);
    t1 += __shfl_xor(t1, 2, 64);  t2 += __shfl_xor(t2, 2, 64);
    t1 += __shfl_xor(t1, 4, 64);  t2 += __shfl_xor(t2, 4, 64);
    t1 += __shfl_xor(t1, 8, 64);  t2 += __shfl_xor(t2, 8, 64);
    t1 += __shfl_xor(t1, 16, 64); t2 += __shfl_xor(t2, 16, 64);
    if ((lane & 31) == 0) {
      float mu = t1 * (1.f / 256.f);
      float var = t2 * (1.f / 256.f) - mu * mu;
      mus[m] = mu;
      rss[m] = rsqrtf(var + 1e-5f);
    }
    u32 p0 = (u32)f2bf(a0.x) | ((u32)f2bf(a0.y) << 16);
    u32 p1 = (u32)f2bf(a0.z) | ((u32)f2bf(a0.w) << 16);
    u32 p2 = (u32)f2bf(a1.x) | ((u32)f2bf(a1.y) << 16);
    u32 p3 = (u32)f2bf(a1.z) | ((u32)f2bf(a1.w) << 16);
    const int sw = (kc & 24) | ((kc & 7) ^ (m & 7));
    *(uint4*)&Asm[m * 256 + sw * 8] = make_uint4(p0, p1, p2, p3);
  }
  __syncthreads();

  const f32x4 Z = {0.f, 0.f, 0.f, 0.f};
  const int b = M0 >> 12;
  const int col = cl;
  const int rq4 = rq * 4;

  for (int oc = 0; oc < 4; oc++) {
    const int O0 = oc * 128;
    f32x4 acc[4][4];
#pragma unroll
    for (int i = 0; i < 4; i++)
#pragma unroll
      for (int j = 0; j < 4; j++) acc[i][j] = Z;

    // barrier-free K-loop: A from LDS (swizzled), B direct from L2-hot global
#pragma unroll 2
    for (int kc8 = 0; kc8 < 8; kc8++) {
      bf16x8 af[4], bfr[4];
      const int c = kc8 * 4 + rq;  // chunk index 0..31
#pragma unroll
      for (int t = 0; t < 4; t++) {
        const int m = wm + t * 16 + cl;
        const int ca = (c & 24) | ((c & 7) ^ (m & 7));
        af[t] = *(const bf16x8*)&Asm[m * 256 + ca * 8];
        const int o = O0 + wn + t * 16 + cl;
        bfr[t] = *(const bf16x8*)(wkvp + (size_t)o * 256 + kc8 * 32 + rq * 8);
      }
#pragma unroll
      for (int i = 0; i < 4; i++)
#pragma unroll
        for (int j = 0; j < 4; j++) acc[i][j] = mfma16(af[i], bfr[j], acc[i][j]);
    }

    // epilogue for this oc chunk
    if (O0 < 256) {  // k output: [b][n][d]
#pragma unroll
      for (int i = 0; i < 4; i++) {
        const int mb = M0 + wm + i * 16 + rq4;
        const int ml = wm + i * 16 + rq4;
        float mu0[4], rs0[4];
#pragma unroll
        for (int r = 0; r < 4; r++) { mu0[r] = mus[ml + r]; rs0[r] = rss[ml + r]; }
#pragma unroll
        for (int j = 0; j < 4; j++) {
          const int o = O0 + wn + j * 16 + col;
          const float ck = ckv[o], dk = dkv[o];
#pragma unroll
          for (int r = 0; r < 4; r++) {
            float val = rs0[r] * acc[i][j][r] - rs0[r] * mu0[r] * ck + dk;
            kbuf[(size_t)(mb + r) * 256 + o] = f2bf(val);
          }
        }
      }
    } else {  // v output, transposed: [b][d][n]
#pragma unroll
      for (int i = 0; i < 4; i++) {
        const int mb = M0 + wm + i * 16 + rq4;
        const int ml = wm + i * 16 + rq4;
        const int n = mb & 4095;
        float mu0[4], rs0[4];
#pragma unroll
        for (int r = 0; r < 4; r++) { mu0[r] = mus[ml + r]; rs0[r] = rss[ml + r]; }
#pragma unroll
        for (int j = 0; j < 4; j++) {
          const int ov = O0 - 256 + wn + j * 16 + col;
          const float ck = ckv[ov + 256], dk = dkv[ov + 256];
          u16 t0 = f2bf(rs0[0] * acc[i][j][0] - rs0[0] * mu0[0] * ck + dk);
          u16 t1 = f2bf(rs0[1] * acc[i][j][1] - rs0[1] * mu0[1] * ck + dk);
          u16 t2 = f2bf(rs0[2] * acc[i][j][2] - rs0[2] * mu0[2] * ck + dk);
          u16 t3 = f2bf(rs0[3] * acc[i][j][3] - rs0[3] * mu0[3] * ck + dk);
          *(ushort4*)(vtbuf + (size_t)(b * 256 + ov) * 4096 + n) = make_ushort4(t0, t1, t2, t3);
        }
      }
    }
  }
}

// ---------------------------------------------------------------------------
// P: fused q + attention pass over a 256-n chunk.
//   phase 0: LN(slots[b]) -> pt rows 0..7 (8..15 zero)   [pt doubles as lnb]
//   phase 1: q = lnb @ Wq^T -> qld (bf16, rows 8..15 compute to zero)
//   phase 2: logits -> softmax(slots) -> P into pt; denom partials
//   phase 3: P·V partials
// Identical numerics to the former slot_q + attn_pass pair (same bf16
// round-trip points, same fragment layouts).
// ---------------------------------------------------------------------------
__global__ void __launch_bounds__(256) attn_pass(
    const float* __restrict__ slots, const float* __restrict__ gs, const float* __restrict__ bs,
    const u16* __restrict__ wqb,
    const u16* __restrict__ kbuf, const u16* __restrict__ vtbuf,
    float* __restrict__ part_acc, float* __restrict__ part_den,
    float* __restrict__ attn_out, int store_attn) {
  __shared__ u16 pt[16 * 264];
  __shared__ u16 qld[16 * 264];
  const int chunk = blockIdx.x;  // 0..15
  const int b = blockIdx.y;      // 0..63
  const int n0 = chunk * 256;
  const int tid = threadIdx.x;
  const int lane = tid & 63;
  const int wv = tid >> 6;
  const int cl = lane & 15;
  const int rq = lane >> 4;
  const f32x4 Z = {0.f, 0.f, 0.f, 0.f};

  // ---- phase 0: LN of slots[b] into pt (lnb role) ----
  for (int i = tid; i < 8 * 264; i += 256) pt[8 * 264 + i] = 0;
  for (int rr = 0; rr < 2; rr++) {
    const int s = wv * 2 + rr;
    float4 x4 = *(const float4*)(slots + ((size_t)b * 8 + s) * 256 + lane * 4);
    float x[4] = {x4.x, x4.y, x4.z, x4.w};
    float s1 = x[0] + x[1] + x[2] + x[3];
    float s2 = x[0] * x[0] + x[1] * x[1] + x[2] * x[2] + x[3] * x[3];
    s1 = wave_sum(s1);
    s2 = wave_sum(s2);
    float mu = s1 * (1.f / 256.f);
    float rstd = rsqrtf(s2 * (1.f / 256.f) - mu * mu + 1e-5f);
    float4 g4 = *(const float4*)(gs + lane * 4);
    float4 b4 = *(const float4*)(bs + lane * 4);
    u16 o4[4];
    o4[0] = f2bf((x[0] - mu) * rstd * g4.x + b4.x);
    o4[1] = f2bf((x[1] - mu) * rstd * g4.y + b4.y);
    o4[2] = f2bf((x[2] - mu) * rstd * g4.z + b4.z);
    o4[3] = f2bf((x[3] - mu) * rstd * g4.w + b4.w);
    *(ushort4*)&pt[s * 264 + lane * 4] = make_ushort4(o4[0], o4[1], o4[2], o4[3]);
  }
  __syncthreads();

  // ---- phase 1: q = lnb @ Wq^T -> qld ----
  {
    bf16x8 af[8];
#pragma unroll
    for (int ks = 0; ks < 8; ks++)
      af[ks] = *(const bf16x8*)&pt[cl * 264 + ks * 32 + rq * 8];
#pragma unroll
    for (int t = 0; t < 4; t++) {
      const int of = wv * 64 + t * 16;
      f32x4 acc = Z;
#pragma unroll
      for (int ks = 0; ks < 8; ks++) {
        bf16x8 bw = *(const bf16x8*)(wqb + (size_t)(of + cl) * 256 + ks * 32 + rq * 8);
        acc = mfma16(af[ks], bw, acc);
      }
#pragma unroll
      for (int r = 0; r < 4; r++)
        qld[(rq * 4 + r) * 264 + of + cl] = f2bf(acc[r]);
    }
  }
  __syncthreads();

  // ---- phase 2: QK^T -> softmax -> P (pt overwritten; all pt reads done) ----
  bf16x8 aq[8];
#pragma unroll
  for (int ks = 0; ks < 8; ks++)
    aq[ks] = *(const bf16x8*)&qld[cl * 264 + ks * 32 + rq * 8];

  float dacc[4] = {0.f, 0.f, 0.f, 0.f};
#pragma unroll
  for (int t = 0; t < 4; t++) {
    const int nl = (wv * 4 + t) * 16;
    f32x4 acc = Z;
    const int n = n0 + nl + cl;
#pragma unroll
    for (int ks = 0; ks < 8; ks++) {
      bf16x8 bk = *(const bf16x8*)(kbuf + ((size_t)b * 4096 + n) * 256 + ks * 32 + rq * 8);
      acc = mfma16(aq[ks], bk, acc);
    }
    float l[4];
#pragma unroll
    for (int r = 0; r < 4; r++) l[r] = acc[r] * 0.0625f;
    float m4 = fmaxf(fmaxf(l[0], l[1]), fmaxf(l[2], l[3]));
    float m8 = fmaxf(m4, __shfl_xor(m4, 16, 64));
    float e[4];
    float s4 = 0.f;
#pragma unroll
    for (int r = 0; r < 4; r++) { e[r] = __expf(l[r] - m8); s4 += e[r]; }
    float s8 = s4 + __shfl_xor(s4, 16, 64);
    float inv = 1.f / s8;
    float pa[4];
#pragma unroll
    for (int r = 0; r < 4; r++) pa[r] = e[r] * inv + 1e-8f;
#pragma unroll
    for (int r = 0; r < 4; r++) pt[(rq * 4 + r) * 264 + nl + cl] = f2bf(pa[r]);
    if (store_attn && lane < 32) {
#pragma unroll
      for (int r = 0; r < 4; r++)
        attn_out[((size_t)b * 8 + rq * 4 + r) * 4096 + n0 + nl + cl] = pa[r];
    }
#pragma unroll
    for (int r = 0; r < 4; r++) dacc[r] += sum16(pa[r]);
  }
  if (cl == 0 && lane < 32) {
#pragma unroll
    for (int r = 0; r < 4; r++)
      part_den[(((size_t)b * 16 + chunk) * 4 + wv) * 8 + rq * 4 + r] = dacc[r];
  }
  __syncthreads();

  // ---- phase 3: P·V ----
  bf16x8 ap[8];
#pragma unroll
  for (int ks = 0; ks < 8; ks++)
    ap[ks] = *(const bf16x8*)&pt[cl * 264 + ks * 32 + rq * 8];
#pragma unroll
  for (int t = 0; t < 4; t++) {
    const int df = wv * 64 + t * 16;
    f32x4 acc = Z;
    const int d = df + cl;
#pragma unroll
    for (int ks = 0; ks < 8; ks++) {
      bf16x8 bv = *(const bf16x8*)(vtbuf + ((size_t)b * 256 + d) * 4096 + n0 + ks * 32 + rq * 8);
      acc = mfma16(ap[ks], bv, acc);
    }
    if (lane < 32) {
#pragma unroll
      for (int r = 0; r < 4; r++)
        part_acc[(((size_t)b * 16 + chunk) * 8 + rq * 4 + r) * 256 + d] = acc[r];
    }
  }
}

// ---------------------------------------------------------------------------
// U: per-batch block: reduce partials -> updates; GRU; LN; MLP; residual.
// ---------------------------------------------------------------------------
__global__ void __launch_bounds__(256) slot_update(
    const float* __restrict__ part_acc, const float* __restrict__ part_den,
    float* __restrict__ slots,
    const u16* __restrict__ wihb, const u16* __restrict__ whhb,
    const float* __restrict__ b_ih, const float* __restrict__ b_hh,
    const float* __restrict__ gm, const float* __restrict__ bm,
    const u16* __restrict__ w1b, const float* __restrict__ b1,
    const u16* __restrict__ w2b, const float* __restrict__ b2,
    float* __restrict__ slots_out, int last) {
  __shared__ u16 ubf[16 * 264];
  __shared__ u16 hbf[16 * 264];
  __shared__ float hf32[8 * 256];
  __shared__ float midf[8 * 256];
  __shared__ u16 h1bf[16 * 1032];
  __shared__ float denl[8];
  const int b = blockIdx.x;
  const int tid = threadIdx.x;
  const int lane = tid & 63;
  const int wv = tid >> 6;
  const int cl = lane & 15;
  const int rq = lane >> 4;
  const f32x4 Z = {0.f, 0.f, 0.f, 0.f};

  for (int i = tid; i < 8 * 264; i += 256) { ubf[8 * 264 + i] = 0; hbf[8 * 264 + i] = 0; }
  if (tid < 8) {
    float s = 0.f;
    for (int c = 0; c < 64; c++) s += part_den[((size_t)b * 64 + c) * 8 + tid];
    denl[tid] = s;
  }
  __syncthreads();

#pragma unroll
  for (int i = 0; i < 8; i++) {
    float s = 0.f;
#pragma unroll
    for (int c = 0; c < 16; c++)
      s += part_acc[(((size_t)b * 16 + c) * 8 + i) * 256 + tid];
    float u = s / denl[i];
    ubf[i * 264 + tid] = f2bf(u);
    float h = slots[((size_t)b * 8 + i) * 256 + tid];
    hf32[i * 256 + tid] = h;
    hbf[i * 264 + tid] = f2bf(h);
  }
  __syncthreads();

  // ---- GRU ----
  bf16x8 au[8], ah[8];
#pragma unroll
  for (int ks = 0; ks < 8; ks++) {
    au[ks] = *(const bf16x8*)&ubf[cl * 264 + ks * 32 + rq * 8];
    ah[ks] = *(const bf16x8*)&hbf[cl * 264 + ks * 32 + rq * 8];
  }
#pragma unroll
  for (int j4 = 0; j4 < 4; j4++) {
    const int j = wv * 4 + j4;  // o-tile 0..15
    f32x4 a_ir = Z, a_iz = Z, a_in = Z, a_hr = Z, a_hz = Z, a_hn = Z;
#pragma unroll
    for (int ks = 0; ks < 8; ks++) {
      const int koff = ks * 32 + rq * 8;
      const int o_r = j * 16 + cl;
      bf16x8 bri = *(const bf16x8*)(wihb + (size_t)o_r * 256 + koff);
      bf16x8 bzi = *(const bf16x8*)(wihb + (size_t)(256 + o_r) * 256 + koff);
      bf16x8 bni = *(const bf16x8*)(wihb + (size_t)(512 + o_r) * 256 + koff);
      bf16x8 brh = *(const bf16x8*)(whhb + (size_t)o_r * 256 + koff);
      bf16x8 bzh = *(const bf16x8*)(whhb + (size_t)(256 + o_r) * 256 + koff);
      bf16x8 bnh = *(const bf16x8*)(whhb + (size_t)(512 + o_r) * 256 + koff);
      a_ir = mfma16(au[ks], bri, a_ir);
      a_iz = mfma16(au[ks], bzi, a_iz);
      a_in = mfma16(au[ks], bni, a_in);
      a_hr = mfma16(ah[ks], brh, a_hr);
      a_hz = mfma16(ah[ks], bzh, a_hz);
      a_hn = mfma16(ah[ks], bnh, a_hn);
    }
    if (lane < 32) {
      const int d = j * 16 + cl;
      const float bihr = b_ih[d], bihz = b_ih[256 + d], bihn = b_ih[512 + d];
      const float bhhr = b_hh[d], bhhz = b_hh[256 + d], bhhn = b_hh[512 + d];
#pragma unroll
      for (int r = 0; r < 4; r++) {
        const int s = rq * 4 + r;
        float ir = a_ir[r] + bihr, iz = a_iz[r] + bihz, inn = a_in[r] + bihn;
        float hr = a_hr[r] + bhhr, hz = a_hz[r] + bhhz, hn = a_hn[r] + bhhn;
        float rg = 1.f / (1.f + __expf(-(ir + hr)));
        float zg = 1.f / (1.f + __expf(-(iz + hz)));
        float ng = tanhf(inn + rg * hn);
        float h = hf32[s * 256 + d];
        midf[s * 256 + d] = (1.f - zg) * ng + zg * h;
      }
    }
  }
  __syncthreads();

  // ---- LN (g_mlp,b_mlp) of midf -> ubf (rows 8-15 still zero) ----
  for (int rr = 0; rr < 2; rr++) {
    const int s = wv * 2 + rr;
    float4 x4 = *(const float4*)&midf[s * 256 + lane * 4];
    float x[4] = {x4.x, x4.y, x4.z, x4.w};
    float s1 = x[0] + x[1] + x[2] + x[3];
    float s2 = x[0] * x[0] + x[1] * x[1] + x[2] * x[2] + x[3] * x[3];
    s1 = wave_sum(s1);
    s2 = wave_sum(s2);
    float mu = s1 * (1.f / 256.f);
    float rstd = rsqrtf(s2 * (1.f / 256.f) - mu * mu + 1e-5f);
    float4 g4 = *(const float4*)(gm + lane * 4);
    float4 b4 = *(const float4*)(bm + lane * 4);
    u16 o4[4];
    o4[0] = f2bf((x[0] - mu) * rstd * g4.x + b4.x);
    o4[1] = f2bf((x[1] - mu) * rstd * g4.y + b4.y);
    o4[2] = f2bf((x[2] - mu) * rstd * g4.z + b4.z);
    o4[3] = f2bf((x[3] - mu) * rstd * g4.w + b4.w);
    *(ushort4*)&ubf[s * 264 + lane * 4] = make_ushort4(o4[0], o4[1], o4[2], o4[3]);
  }
  __syncthreads();

  // ---- MLP1: relu(ln @ W1^T + b1) -> h1bf ----
  bf16x8 al[8];
#pragma unroll
  for (int ks = 0; ks < 8; ks++)
    al[ks] = *(const bf16x8*)&ubf[cl * 264 + ks * 32 + rq * 8];
#pragma unroll
  for (int t = 0; t < 16; t++) {
    const int of = wv * 256 + t * 16;
    f32x4 acc = Z;
#pragma unroll
    for (int ks = 0; ks < 8; ks++) {
      bf16x8 bw = *(const bf16x8*)(w1b + (size_t)(of + cl) * 256 + ks * 32 + rq * 8);
      acc = mfma16(al[ks], bw, acc);
    }
    const float bb = b1[of + cl];
#pragma unroll
    for (int r = 0; r < 4; r++)
      h1bf[(rq * 4 + r) * 1032 + of + cl] = f2bf(fmaxf(acc[r] + bb, 0.f));
  }
  __syncthreads();

  // ---- MLP2: mid + h1 @ W2^T + b2 -> slots (and out on last iter) ----
  f32x4 acc2[4] = {Z, Z, Z, Z};
  for (int ks = 0; ks < 32; ks++) {
    bf16x8 ah1 = *(const bf16x8*)&h1bf[cl * 1032 + ks * 32 + rq * 8];
#pragma unroll
    for (int t = 0; t < 4; t++) {
      const int o = wv * 64 + t * 16 + cl;
      bf16x8 bw = *(const bf16x8*)(w2b + (size_t)o * 1024 + ks * 32 + rq * 8);
      acc2[t] = mfma16(ah1, bw, acc2[t]);
    }
  }
  if (lane < 32) {
#pragma unroll
    for (int t = 0; t < 4; t++) {
      const int o = wv * 64 + t * 16 + cl;
      const float bb = b2[o];
#pragma unroll
      for (int r = 0; r < 4; r++) {
        const int s = rq * 4 + r;
        float val = midf[s * 256 + o] + acc2[t][r] + bb;
        slots[((size_t)b * 8 + s) * 256 + o] = val;
        if (last) slots_out[((size_t)b * 8 + s) * 256 + o] = val;
      }
    }
  }
}

// ---------------------------------------------------------------------------
extern "C" void kernel_launch(void* const* d_in, const int* in_sizes, int n_in,
                              void* d_out, int out_size, void* d_ws, size_t ws_size,
                              hipStream_t stream) {
  (void)in_sizes; (void)n_in; (void)out_size;
  const float* features = (const float*)d_in[0];
  const float* slots_init = (const float*)d_in[1];
  const float* g_feat = (const float*)d_in[2];
  const float* b_feat = (const float*)d_in[3];
  const float* g_slots = (const float*)d_in[4];
  const float* b_slots = (const float*)d_in[5];
  const float* g_mlp = (const float*)d_in[6];
  const float* b_mlp = (const float*)d_in[7];
  const float* Wk = (const float*)d_in[8];
  const float* Wv = (const float*)d_in[9];
  const float* Wq = (const float*)d_in[10];
  const float* w_ih = (const float*)d_in[11];
  const float* w_hh = (const float*)d_in[12];
  const float* b_ih = (const float*)d_in[13];
  const float* b_hh = (const float*)d_in[14];
  const float* W1 = (const float*)d_in[15];
  const float* b1 = (const float*)d_in[16];
  const float* W2 = (const float*)d_in[17];
  const float* b2 = (const float*)d_in[18];

  // Workspace layout (bytes). Total = 280,236,032.
  const size_t REQUIRED = 280236032ull;
  if (ws_size < REQUIRED) return;

  char* ws = (char*)d_ws;
  u16* kbuf = (u16*)(ws + 0);                  // 134,217,728
  u16* vtbuf = (u16*)(ws + 134217728);         // 134,217,728
  // qbuf slot (ws + 268435456, 524,288 B) now unused — q fused into attn_pass
  float* part_acc = (float*)(ws + 268959744);  // 8,388,608
  float* part_den = (float*)(ws + 277348352);  // 131,072  [b][chunk][wave][8]
  float* slots = (float*)(ws + 277479424);     // 524,288
  u16* wkvp = (u16*)(ws + 278003712);          // 262,144
  float* ckv = (float*)(ws + 278265856);       // 2,048
  float* dkv = (float*)(ws + 278267904);       // 2,048
  u16* wqb = (u16*)(ws + 278269952);           // 131,072
  u16* wihb = (u16*)(ws + 278401024);          // 393,216
  u16* whhb = (u16*)(ws + 278794240);          // 393,216
  u16* w1b = (u16*)(ws + 279187456);           // 524,288
  u16* w2b = (u16*)(ws + 279711744);           // 524,288

  float* out_slots = (float*)d_out;
  float* out_attn = out_slots + 131072;

  init_prep<<<1216, 256, 0, stream>>>(Wk, Wv, g_feat, b_feat, slots_init, Wq, w_ih, w_hh, W1, W2,
                                      wkvp, ckv, dkv, slots, wqb, wihb, whhb, w1b, w2b);
  gemm_kv<<<2048, 256, 0, stream>>>(features, wkvp, ckv, dkv, kbuf, vtbuf);
  for (int it = 0; it < 3; it++) {
    attn_pass<<<dim3(16, 64), 256, 0, stream>>>(slots, g_slots, b_slots, wqb, kbuf, vtbuf,
                                                part_acc, part_den, out_attn, it == 2 ? 1 : 0);
    slot_update<<<64, 256, 0, stream>>>(part_acc, part_den, slots, wihb, whhb, b_ih, b_hh,
                                        g_mlp, b_mlp, w1b, b1, w2b, b2, out_slots, it == 2 ? 1 : 0);
  }
}

// Round 3
// 891.439 us; speedup vs baseline: 1.0578x; 1.0578x over previous
//
#include <hip/hip_runtime.h>
#include <stdint.h>

typedef unsigned short u16;
typedef unsigned int u32;
typedef __bf16 bf16_t;
typedef bf16_t bf16x8 __attribute__((ext_vector_type(8)));
typedef float f32x4 __attribute__((ext_vector_type(4)));

#define DEV static __device__ __forceinline__

DEV float bf2f(u16 a) {
  union { u32 u; float f; } c; c.u = ((u32)a) << 16; return c.f;
}
DEV u16 f2bf(float f) {
  union { float f; u32 u; } c; c.f = f;
  return (u16)((c.u + 0x7FFFu + ((c.u >> 16) & 1u)) >> 16);
}
DEV f32x4 mfma16(bf16x8 a, bf16x8 b, f32x4 c) {
  return __builtin_amdgcn_mfma_f32_16x16x32_bf16(a, b, c, 0, 0, 0);
}
DEV float wave_sum(float v) {
#pragma unroll
  for (int off = 32; off > 0; off >>= 1) v += __shfl_xor(v, off, 64);
  return v;
}
DEV float sum16(float v) {
  v += __shfl_xor(v, 1, 64);
  v += __shfl_xor(v, 2, 64);
  v += __shfl_xor(v, 4, 64);
  v += __shfl_xor(v, 8, 64);
  return v;
}

// ---------------------------------------------------------------------------
// INIT: slots copy; bf16 conversion of Wq / w_ih / w_hh / W1 / W2 / Wv;
// Wk transposed -> wktb (bf16). All inputs fp32.
//   blk 0..127    : slots copy
//   blk 128..1151 : concat convert [Wq | w_ih | w_hh | W1 | W2 | Wv]
//   blk 1152..1167: Wk 64x64-tile LDS transpose -> wktb[e][d] = Wk[d][e]
// ---------------------------------------------------------------------------
__global__ void __launch_bounds__(256) init_prep(
    const float* __restrict__ Wk, const float* __restrict__ Wv,
    const float* __restrict__ slots_init,
    const float* __restrict__ Wq, const float* __restrict__ w_ih,
    const float* __restrict__ w_hh, const float* __restrict__ W1,
    const float* __restrict__ W2,
    float* __restrict__ slots,
    u16* __restrict__ wqb, u16* __restrict__ wihb, u16* __restrict__ whhb,
    u16* __restrict__ w1b, u16* __restrict__ w2b,
    u16* __restrict__ wvb, u16* __restrict__ wktb) {
  const int blk = blockIdx.x;
  const int tid = threadIdx.x;
  if (blk < 128) {
    const int idx = blk * 1024 + tid * 4;
    *(float4*)(slots + idx) = *(const float4*)(slots_init + idx);
  } else if (blk < 1152) {
    const int i = (blk - 128) * 1024 + tid * 4;
    const float* src; u16* dst; int off;
    if (i < 65536)       { src = Wq;   dst = wqb;  off = i; }
    else if (i < 262144) { src = w_ih; dst = wihb; off = i - 65536; }
    else if (i < 458752) { src = w_hh; dst = whhb; off = i - 262144; }
    else if (i < 720896) { src = W1;   dst = w1b;  off = i - 458752; }
    else if (i < 983040) { src = W2;   dst = w2b;  off = i - 720896; }
    else                 { src = Wv;   dst = wvb;  off = i - 983040; }
    float4 v = *(const float4*)(src + off);
    *(ushort4*)(dst + off) = make_ushort4(f2bf(v.x), f2bf(v.y), f2bf(v.z), f2bf(v.w));
  } else {
    // 64x64 tile transpose of Wk into wktb
    __shared__ u16 tl[64][66];
    const int tb = blk - 1152;          // 0..15
    const int r0 = (tb >> 2) * 64;      // Wk row tile
    const int c0 = (tb & 3) * 64;       // Wk col tile
    const int r = tid >> 2;             // 0..63
    const int cseg = (tid & 3) * 16;
#pragma unroll
    for (int q = 0; q < 4; q++) {
      float4 v = *(const float4*)(Wk + (size_t)(r0 + r) * 256 + c0 + cseg + q * 4);
      tl[r][cseg + q * 4 + 0] = f2bf(v.x);
      tl[r][cseg + q * 4 + 1] = f2bf(v.y);
      tl[r][cseg + q * 4 + 2] = f2bf(v.z);
      tl[r][cseg + q * 4 + 3] = f2bf(v.w);
    }
    __syncthreads();
    const int c = tid >> 2;             // output row within tile (e index)
    const int rseg = (tid & 3) * 16;
    u16 out[16];
#pragma unroll
    for (int j = 0; j < 16; j++) out[j] = tl[rseg + j][c];
#pragma unroll
    for (int q = 0; q < 4; q++)
      *(ushort4*)(wktb + (size_t)(c0 + c) * 256 + r0 + rseg + q * 4) =
          make_ushort4(out[q * 4], out[q * 4 + 1], out[q * 4 + 2], out[q * 4 + 3]);
  }
}

// ---------------------------------------------------------------------------
// LN_FEAT: pure streaming LayerNorm of features (g,b applied) -> bf16,
// stored both as fbuf [b][n][d] and fbuf_t [b][d][n]. 64-row tiles.
// No GEMM here: Wk folded into attn (qk), Wv folded into slot_update.
// ---------------------------------------------------------------------------
__global__ void __launch_bounds__(256) ln_feat(
    const float* __restrict__ feat, const float* __restrict__ g,
    const float* __restrict__ bia,
    u16* __restrict__ fbuf, u16* __restrict__ fbuf_t) {
  __shared__ u16 T[64 * 264];  // 33 KB, row pitch 264 u16
  const int tid = threadIdx.x;
  const int M0 = blockIdx.x * 64;
  const int b = M0 >> 12;
  const int nb = M0 & 4095;

  // ---- phase A: load fp32, LN per row, write fbuf rows + LDS tile ----
#pragma unroll 2
  for (int i = 0; i < 8; i++) {
    const int gr = i * 256 + tid;
    const int m = gr >> 5;   // row 0..63 (32 consecutive threads per row)
    const int kc = gr & 31;  // 16B-of-bf16 chunk (8 floats)
    const float* fp = feat + (size_t)(M0 + m) * 256 + kc * 8;
    float4 a0 = *(const float4*)fp;
    float4 a1 = *(const float4*)(fp + 4);
    float t1 = a0.x + a0.y + a0.z + a0.w + a1.x + a1.y + a1.z + a1.w;
    float t2 = a0.x * a0.x + a0.y * a0.y + a0.z * a0.z + a0.w * a0.w +
               a1.x * a1.x + a1.y * a1.y + a1.z * a1.z + a1.w * a1.w;
    t1 += __shfl_xor(t1, 1, 64);  t2 += __shfl_xor(t2, 1, 64);
    t1 += __shfl_xor(t1, 2, 64);  t2 += __shfl_xor(t2, 2, 64);
    t1 += __shfl_xor(t1, 4, 64);  t2 += __shfl_xor(t2, 4, 64);
    t1 += __shfl_xor(t1, 8, 64);  t2 += __shfl_xor(t2, 8, 64);
    t1 += __shfl_xor(t1, 16, 64); t2 += __shfl_xor(t2, 16, 64);
    const float mu = t1 * (1.f / 256.f);
    const float rs = rsqrtf(t2 * (1.f / 256.f) - mu * mu + 1e-5f);
    float4 g0 = *(const float4*)(g + kc * 8);
    float4 g1 = *(const float4*)(g + kc * 8 + 4);
    float4 b0 = *(const float4*)(bia + kc * 8);
    float4 b1 = *(const float4*)(bia + kc * 8 + 4);
    u16 y[8];
    y[0] = f2bf((a0.x - mu) * rs * g0.x + b0.x);
    y[1] = f2bf((a0.y - mu) * rs * g0.y + b0.y);
    y[2] = f2bf((a0.z - mu) * rs * g0.z + b0.z);
    y[3] = f2bf((a0.w - mu) * rs * g0.w + b0.w);
    y[4] = f2bf((a1.x - mu) * rs * g1.x + b1.x);
    y[5] = f2bf((a1.y - mu) * rs * g1.y + b1.y);
    y[6] = f2bf((a1.z - mu) * rs * g1.z + b1.z);
    y[7] = f2bf((a1.w - mu) * rs * g1.w + b1.w);
    uint4 pk = make_uint4((u32)y[0] | ((u32)y[1] << 16), (u32)y[2] | ((u32)y[3] << 16),
                          (u32)y[4] | ((u32)y[5] << 16), (u32)y[6] | ((u32)y[7] << 16));
    *(uint4*)&T[m * 264 + kc * 8] = pk;
    *(uint4*)(fbuf + (size_t)(M0 + m) * 256 + kc * 8) = pk;
  }
  __syncthreads();

  // ---- phase C: transposed write fbuf_t [b][d][n] ----
  const int dl = tid >> 4;        // 0..15
  const int ns4 = (tid & 15) * 4; // n-local 0..60
#pragma unroll 4
  for (int o = 0; o < 16; o++) {
    const int d = dl + o * 16;
    u16 v0 = T[(ns4 + 0) * 264 + d];
    u16 v1 = T[(ns4 + 1) * 264 + d];
    u16 v2 = T[(ns4 + 2) * 264 + d];
    u16 v3 = T[(ns4 + 3) * 264 + d];
    *(ushort4*)(fbuf_t + ((size_t)b * 256 + d) * 4096 + nb + ns4) = make_ushort4(v0, v1, v2, v3);
  }
}

// ---------------------------------------------------------------------------
// P: fused q + attention pass over a 256-n chunk.
//   phase 0 : LN(slots[b]) -> pt rows 0..7 (8..15 zero)
//   phase 1 : q  = lnb @ Wq^T            -> qld
//   phase 1b: qk = q @ Wk (via wktb)     -> pt   (logits basis vector)
//   phase 2 : logits = qk @ f_ln^T (fbuf) -> softmax(slots) -> P -> qld
//   phase 3 : Pf partial = P @ f_ln (fbuf_t) -> part_acc
// ---------------------------------------------------------------------------
__global__ void __launch_bounds__(256) attn_pass(
    const float* __restrict__ slots, const float* __restrict__ gs, const float* __restrict__ bs,
    const u16* __restrict__ wqb, const u16* __restrict__ wktb,
    const u16* __restrict__ fbuf, const u16* __restrict__ fbuf_t,
    float* __restrict__ part_acc, float* __restrict__ part_den,
    float* __restrict__ attn_out, int store_attn) {
  __shared__ u16 pt[16 * 264];
  __shared__ u16 qld[16 * 264];
  const int chunk = blockIdx.x;  // 0..15
  const int b = blockIdx.y;      // 0..63
  const int n0 = chunk * 256;
  const int tid = threadIdx.x;
  const int lane = tid & 63;
  const int wv = tid >> 6;
  const int cl = lane & 15;
  const int rq = lane >> 4;
  const f32x4 Z = {0.f, 0.f, 0.f, 0.f};

  // ---- phase 0: LN of slots[b] into pt ----
  for (int i = tid; i < 8 * 264; i += 256) pt[8 * 264 + i] = 0;
  for (int rr = 0; rr < 2; rr++) {
    const int s = wv * 2 + rr;
    float4 x4 = *(const float4*)(slots + ((size_t)b * 8 + s) * 256 + lane * 4);
    float x[4] = {x4.x, x4.y, x4.z, x4.w};
    float s1 = x[0] + x[1] + x[2] + x[3];
    float s2 = x[0] * x[0] + x[1] * x[1] + x[2] * x[2] + x[3] * x[3];
    s1 = wave_sum(s1);
    s2 = wave_sum(s2);
    float mu = s1 * (1.f / 256.f);
    float rstd = rsqrtf(s2 * (1.f / 256.f) - mu * mu + 1e-5f);
    float4 g4 = *(const float4*)(gs + lane * 4);
    float4 b4 = *(const float4*)(bs + lane * 4);
    u16 o4[4];
    o4[0] = f2bf((x[0] - mu) * rstd * g4.x + b4.x);
    o4[1] = f2bf((x[1] - mu) * rstd * g4.y + b4.y);
    o4[2] = f2bf((x[2] - mu) * rstd * g4.z + b4.z);
    o4[3] = f2bf((x[3] - mu) * rstd * g4.w + b4.w);
    *(ushort4*)&pt[s * 264 + lane * 4] = make_ushort4(o4[0], o4[1], o4[2], o4[3]);
  }
  __syncthreads();

  // ---- phase 1: q = lnb @ Wq^T -> qld ----
  {
    bf16x8 af[8];
#pragma unroll
    for (int ks = 0; ks < 8; ks++)
      af[ks] = *(const bf16x8*)&pt[cl * 264 + ks * 32 + rq * 8];
#pragma unroll
    for (int t = 0; t < 4; t++) {
      const int of = wv * 64 + t * 16;
      f32x4 acc = Z;
#pragma unroll
      for (int ks = 0; ks < 8; ks++) {
        bf16x8 bw = *(const bf16x8*)(wqb + (size_t)(of + cl) * 256 + ks * 32 + rq * 8);
        acc = mfma16(af[ks], bw, acc);
      }
#pragma unroll
      for (int r = 0; r < 4; r++)
        qld[(rq * 4 + r) * 264 + of + cl] = f2bf(acc[r]);
    }
  }
  __syncthreads();

  // ---- phase 1b: qk = q @ Wk -> pt (overwrites lnb; lnb reads done) ----
  {
    bf16x8 a2[8];
#pragma unroll
    for (int ks = 0; ks < 8; ks++)
      a2[ks] = *(const bf16x8*)&qld[cl * 264 + ks * 32 + rq * 8];
#pragma unroll
    for (int t = 0; t < 4; t++) {
      const int of = wv * 64 + t * 16;
      f32x4 acc = Z;
#pragma unroll
      for (int ks = 0; ks < 8; ks++) {
        bf16x8 bw = *(const bf16x8*)(wktb + (size_t)(of + cl) * 256 + ks * 32 + rq * 8);
        acc = mfma16(a2[ks], bw, acc);
      }
#pragma unroll
      for (int r = 0; r < 4; r++)
        pt[(rq * 4 + r) * 264 + of + cl] = f2bf(acc[r]);
    }
  }
  __syncthreads();

  // ---- phase 2: logits = qk @ f_ln^T -> softmax -> P into qld ----
  bf16x8 aq[8];
#pragma unroll
  for (int ks = 0; ks < 8; ks++)
    aq[ks] = *(const bf16x8*)&pt[cl * 264 + ks * 32 + rq * 8];

  float dacc[4] = {0.f, 0.f, 0.f, 0.f};
#pragma unroll
  for (int t = 0; t < 4; t++) {
    const int nl = (wv * 4 + t) * 16;
    f32x4 acc = Z;
    const int n = n0 + nl + cl;
#pragma unroll
    for (int ks = 0; ks < 8; ks++) {
      bf16x8 bk = *(const bf16x8*)(fbuf + ((size_t)b * 4096 + n) * 256 + ks * 32 + rq * 8);
      acc = mfma16(aq[ks], bk, acc);
    }
    float l[4];
#pragma unroll
    for (int r = 0; r < 4; r++) l[r] = acc[r] * 0.0625f;
    float m4 = fmaxf(fmaxf(l[0], l[1]), fmaxf(l[2], l[3]));
    float m8 = fmaxf(m4, __shfl_xor(m4, 16, 64));
    float e[4];
    float s4 = 0.f;
#pragma unroll
    for (int r = 0; r < 4; r++) { e[r] = __expf(l[r] - m8); s4 += e[r]; }
    float s8 = s4 + __shfl_xor(s4, 16, 64);
    float inv = 1.f / s8;
    float pa[4];
#pragma unroll
    for (int r = 0; r < 4; r++) pa[r] = e[r] * inv + 1e-8f;
#pragma unroll
    for (int r = 0; r < 4; r++) qld[(rq * 4 + r) * 264 + nl + cl] = f2bf(pa[r]);
    if (store_attn && lane < 32) {
#pragma unroll
      for (int r = 0; r < 4; r++)
        attn_out[((size_t)b * 8 + rq * 4 + r) * 4096 + n0 + nl + cl] = pa[r];
    }
#pragma unroll
    for (int r = 0; r < 4; r++) dacc[r] += sum16(pa[r]);
  }
  if (cl == 0 && lane < 32) {
#pragma unroll
    for (int r = 0; r < 4; r++)
      part_den[(((size_t)b * 16 + chunk) * 4 + wv) * 8 + rq * 4 + r] = dacc[r];
  }
  __syncthreads();

  // ---- phase 3: Pf = P @ f_ln (fbuf_t) ----
  bf16x8 ap[8];
#pragma unroll
  for (int ks = 0; ks < 8; ks++)
    ap[ks] = *(const bf16x8*)&qld[cl * 264 + ks * 32 + rq * 8];
#pragma unroll
  for (int t = 0; t < 4; t++) {
    const int df = wv * 64 + t * 16;
    f32x4 acc = Z;
    const int d = df + cl;
#pragma unroll
    for (int ks = 0; ks < 8; ks++) {
      bf16x8 bv = *(const bf16x8*)(fbuf_t + ((size_t)b * 256 + d) * 4096 + n0 + ks * 32 + rq * 8);
      acc = mfma16(ap[ks], bv, acc);
    }
    if (lane < 32) {
#pragma unroll
      for (int r = 0; r < 4; r++)
        part_acc[(((size_t)b * 16 + chunk) * 8 + rq * 4 + r) * 256 + d] = acc[r];
    }
  }
}

// ---------------------------------------------------------------------------
// U: reduce partials -> Pf_norm; updates = Pf_norm @ Wv^T; GRU; LN; MLP; res.
// ---------------------------------------------------------------------------
__global__ void __launch_bounds__(256) slot_update(
    const float* __restrict__ part_acc, const float* __restrict__ part_den,
    float* __restrict__ slots,
    const u16* __restrict__ wihb, const u16* __restrict__ whhb,
    const float* __restrict__ b_ih, const float* __restrict__ b_hh,
    const float* __restrict__ gm, const float* __restrict__ bm,
    const u16* __restrict__ w1b, const float* __restrict__ b1,
    const u16* __restrict__ w2b, const float* __restrict__ b2,
    const u16* __restrict__ wvb,
    float* __restrict__ slots_out, int last) {
  __shared__ u16 ubf[16 * 264];
  __shared__ u16 hbf[16 * 264];
  __shared__ u16 updbf[16 * 264];
  __shared__ float hf32[8 * 256];
  __shared__ float midf[8 * 256];
  __shared__ u16 h1bf[16 * 1032];
  __shared__ float denl[8];
  const int b = blockIdx.x;
  const int tid = threadIdx.x;
  const int lane = tid & 63;
  const int wv = tid >> 6;
  const int cl = lane & 15;
  const int rq = lane >> 4;
  const f32x4 Z = {0.f, 0.f, 0.f, 0.f};

  for (int i = tid; i < 8 * 264; i += 256) { ubf[8 * 264 + i] = 0; hbf[8 * 264 + i] = 0; }
  if (tid < 8) {
    float s = 0.f;
    for (int c = 0; c < 64; c++) s += part_den[((size_t)b * 64 + c) * 8 + tid];
    denl[tid] = s;
  }
  __syncthreads();

#pragma unroll
  for (int i = 0; i < 8; i++) {
    float s = 0.f;
#pragma unroll
    for (int c = 0; c < 16; c++)
      s += part_acc[(((size_t)b * 16 + c) * 8 + i) * 256 + tid];
    float u = s / denl[i];
    ubf[i * 264 + tid] = f2bf(u);          // Pf_norm (attn_wm @ f_ln)
    float h = slots[((size_t)b * 8 + i) * 256 + tid];
    hf32[i * 256 + tid] = h;
    hbf[i * 264 + tid] = f2bf(h);
  }
  __syncthreads();

  // ---- updates = Pf_norm @ Wv^T -> updbf ----
  {
    bf16x8 apf[8];
#pragma unroll
    for (int ks = 0; ks < 8; ks++)
      apf[ks] = *(const bf16x8*)&ubf[cl * 264 + ks * 32 + rq * 8];
#pragma unroll
    for (int t = 0; t < 4; t++) {
      const int of = wv * 64 + t * 16;
      f32x4 acc = Z;
#pragma unroll
      for (int ks = 0; ks < 8; ks++) {
        bf16x8 bw = *(const bf16x8*)(wvb + (size_t)(of + cl) * 256 + ks * 32 + rq * 8);
        acc = mfma16(apf[ks], bw, acc);
      }
#pragma unroll
      for (int r = 0; r < 4; r++)
        updbf[(rq * 4 + r) * 264 + of + cl] = f2bf(acc[r]);
    }
  }
  __syncthreads();

  // ---- GRU ----
  bf16x8 au[8], ah[8];
#pragma unroll
  for (int ks = 0; ks < 8; ks++) {
    au[ks] = *(const bf16x8*)&updbf[cl * 264 + ks * 32 + rq * 8];
    ah[ks] = *(const bf16x8*)&hbf[cl * 264 + ks * 32 + rq * 8];
  }
#pragma unroll
  for (int j4 = 0; j4 < 4; j4++) {
    const int j = wv * 4 + j4;  // o-tile 0..15
    f32x4 a_ir = Z, a_iz = Z, a_in = Z, a_hr = Z, a_hz = Z, a_hn = Z;
#pragma unroll
    for (int ks = 0; ks < 8; ks++) {
      const int koff = ks * 32 + rq * 8;
      const int o_r = j * 16 + cl;
      bf16x8 bri = *(const bf16x8*)(wihb + (size_t)o_r * 256 + koff);
      bf16x8 bzi = *(const bf16x8*)(wihb + (size_t)(256 + o_r) * 256 + koff);
      bf16x8 bni = *(const bf16x8*)(wihb + (size_t)(512 + o_r) * 256 + koff);
      bf16x8 brh = *(const bf16x8*)(whhb + (size_t)o_r * 256 + koff);
      bf16x8 bzh = *(const bf16x8*)(whhb + (size_t)(256 + o_r) * 256 + koff);
      bf16x8 bnh = *(const bf16x8*)(whhb + (size_t)(512 + o_r) * 256 + koff);
      a_ir = mfma16(au[ks], bri, a_ir);
      a_iz = mfma16(au[ks], bzi, a_iz);
      a_in = mfma16(au[ks], bni, a_in);
      a_hr = mfma16(ah[ks], brh, a_hr);
      a_hz = mfma16(ah[ks], bzh, a_hz);
      a_hn = mfma16(ah[ks], bnh, a_hn);
    }
    if (lane < 32) {
      const int d = j * 16 + cl;
      const float bihr = b_ih[d], bihz = b_ih[256 + d], bihn = b_ih[512 + d];
      const float bhhr = b_hh[d], bhhz = b_hh[256 + d], bhhn = b_hh[512 + d];
#pragma unroll
      for (int r = 0; r < 4; r++) {
        const int s = rq * 4 + r;
        float ir = a_ir[r] + bihr, iz = a_iz[r] + bihz, inn = a_in[r] + bihn;
        float hr = a_hr[r] + bhhr, hz = a_hz[r] + bhhz, hn = a_hn[r] + bhhn;
        float rg = 1.f / (1.f + __expf(-(ir + hr)));
        float zg = 1.f / (1.f + __expf(-(iz + hz)));
        float ng = tanhf(inn + rg * hn);
        float h = hf32[s * 256 + d];
        midf[s * 256 + d] = (1.f - zg) * ng + zg * h;
      }
    }
  }
  __syncthreads();

  // ---- LN (g_mlp,b_mlp) of midf -> ubf (rows 8-15 still zero) ----
  for (int rr = 0; rr < 2; rr++) {
    const int s = wv * 2 + rr;
    float4 x4 = *(const float4*)&midf[s * 256 + lane * 4];
    float x[4] = {x4.x, x4.y, x4.z, x4.w};
    float s1 = x[0] + x[1] + x[2] + x[3];
    float s2 = x[0] * x[0] + x[1] * x[1] + x[2] * x[2] + x[3] * x[3];
    s1 = wave_sum(s1);
    s2 = wave_sum(s2);
    float mu = s1 * (1.f / 256.f);
    float rstd = rsqrtf(s2 * (1.f / 256.f) - mu * mu + 1e-5f);
    float4 g4 = *(const float4*)(gm + lane * 4);
    float4 b4 = *(const float4*)(bm + lane * 4);
    u16 o4[4];
    o4[0] = f2bf((x[0] - mu) * rstd * g4.x + b4.x);
    o4[1] = f2bf((x[1] - mu) * rstd * g4.y + b4.y);
    o4[2] = f2bf((x[2] - mu) * rstd * g4.z + b4.z);
    o4[3] = f2bf((x[3] - mu) * rstd * g4.w + b4.w);
    *(ushort4*)&ubf[s * 264 + lane * 4] = make_ushort4(o4[0], o4[1], o4[2], o4[3]);
  }
  __syncthreads();

  // ---- MLP1: relu(ln @ W1^T + b1) -> h1bf ----
  bf16x8 al[8];
#pragma unroll
  for (int ks = 0; ks < 8; ks++)
    al[ks] = *(const bf16x8*)&ubf[cl * 264 + ks * 32 + rq * 8];
#pragma unroll
  for (int t = 0; t < 16; t++) {
    const int of = wv * 256 + t * 16;
    f32x4 acc = Z;
#pragma unroll
    for (int ks = 0; ks < 8; ks++) {
      bf16x8 bw = *(const bf16x8*)(w1b + (size_t)(of + cl) * 256 + ks * 32 + rq * 8);
      acc = mfma16(al[ks], bw, acc);
    }
    const float bb = b1[of + cl];
#pragma unroll
    for (int r = 0; r < 4; r++)
      h1bf[(rq * 4 + r) * 1032 + of + cl] = f2bf(fmaxf(acc[r] + bb, 0.f));
  }
  __syncthreads();

  // ---- MLP2: mid + h1 @ W2^T + b2 -> slots (and out on last iter) ----
  f32x4 acc2[4] = {Z, Z, Z, Z};
  for (int ks = 0; ks < 32; ks++) {
    bf16x8 ah1 = *(const bf16x8*)&h1bf[cl * 1032 + ks * 32 + rq * 8];
#pragma unroll
    for (int t = 0; t < 4; t++) {
      const int o = wv * 64 + t * 16 + cl;
      bf16x8 bw = *(const bf16x8*)(w2b + (size_t)o * 1024 + ks * 32 + rq * 8);
      acc2[t] = mfma16(ah1, bw, acc2[t]);
    }
  }
  if (lane < 32) {
#pragma unroll
    for (int t = 0; t < 4; t++) {
      const int o = wv * 64 + t * 16 + cl;
      const float bb = b2[o];
#pragma unroll
      for (int r = 0; r < 4; r++) {
        const int s = rq * 4 + r;
        float val = midf[s * 256 + o] + acc2[t][r] + bb;
        slots[((size_t)b * 8 + s) * 256 + o] = val;
        if (last) slots_out[((size_t)b * 8 + s) * 256 + o] = val;
      }
    }
  }
}

// ---------------------------------------------------------------------------
extern "C" void kernel_launch(void* const* d_in, const int* in_sizes, int n_in,
                              void* d_out, int out_size, void* d_ws, size_t ws_size,
                              hipStream_t stream) {
  (void)in_sizes; (void)n_in; (void)out_size;
  const float* features = (const float*)d_in[0];
  const float* slots_init = (const float*)d_in[1];
  const float* g_feat = (const float*)d_in[2];
  const float* b_feat = (const float*)d_in[3];
  const float* g_slots = (const float*)d_in[4];
  const float* b_slots = (const float*)d_in[5];
  const float* g_mlp = (const float*)d_in[6];
  const float* b_mlp = (const float*)d_in[7];
  const float* Wk = (const float*)d_in[8];
  const float* Wv = (const float*)d_in[9];
  const float* Wq = (const float*)d_in[10];
  const float* w_ih = (const float*)d_in[11];
  const float* w_hh = (const float*)d_in[12];
  const float* b_ih = (const float*)d_in[13];
  const float* b_hh = (const float*)d_in[14];
  const float* W1 = (const float*)d_in[15];
  const float* b1 = (const float*)d_in[16];
  const float* W2 = (const float*)d_in[17];
  const float* b2 = (const float*)d_in[18];

  // Workspace layout (bytes). Total = 280,236,032 (unchanged).
  const size_t REQUIRED = 280236032ull;
  if (ws_size < REQUIRED) return;

  char* ws = (char*)d_ws;
  u16* fbuf = (u16*)(ws + 0);                  // 134,217,728  LN(feat) [b][n][d]
  u16* fbuf_t = (u16*)(ws + 134217728);        // 134,217,728  LN(feat) [b][d][n]
  float* part_acc = (float*)(ws + 268959744);  // 8,388,608
  float* part_den = (float*)(ws + 277348352);  // 131,072
  float* slots = (float*)(ws + 277479424);     // 524,288
  u16* wktb = (u16*)(ws + 278003712);          // 131,072  Wk^T bf16
  u16* wvb = (u16*)(ws + 278134784);           // 131,072  Wv bf16
  u16* wqb = (u16*)(ws + 278269952);           // 131,072
  u16* wihb = (u16*)(ws + 278401024);          // 393,216
  u16* whhb = (u16*)(ws + 278794240);          // 393,216
  u16* w1b = (u16*)(ws + 279187456);           // 524,288
  u16* w2b = (u16*)(ws + 279711744);           // 524,288

  float* out_slots = (float*)d_out;
  float* out_attn = out_slots + 131072;

  init_prep<<<1168, 256, 0, stream>>>(Wk, Wv, slots_init, Wq, w_ih, w_hh, W1, W2,
                                      slots, wqb, wihb, whhb, w1b, w2b, wvb, wktb);
  ln_feat<<<4096, 256, 0, stream>>>(features, g_feat, b_feat, fbuf, fbuf_t);
  for (int it = 0; it < 3; it++) {
    attn_pass<<<dim3(16, 64), 256, 0, stream>>>(slots, g_slots, b_slots, wqb, wktb,
                                                fbuf, fbuf_t, part_acc, part_den,
                                                out_attn, it == 2 ? 1 : 0);
    slot_update<<<64, 256, 0, stream>>>(part_acc, part_den, slots, wihb, whhb, b_ih, b_hh,
                                        g_mlp, b_mlp, w1b, b1, w2b, b2, wvb,
                                        out_slots, it == 2 ? 1 : 0);
  }
}

// Round 4
// 837.511 us; speedup vs baseline: 1.1259x; 1.0644x over previous
//
#include <hip/hip_runtime.h>
#include <stdint.h>

typedef unsigned short u16;
typedef unsigned int u32;
typedef __bf16 bf16_t;
typedef bf16_t bf16x8 __attribute__((ext_vector_type(8)));
typedef float f32x4 __attribute__((ext_vector_type(4)));

#define DEV static __device__ __forceinline__

DEV float bf2f(u16 a) {
  union { u32 u; float f; } c; c.u = ((u32)a) << 16; return c.f;
}
DEV u16 f2bf(float f) {
  union { float f; u32 u; } c; c.f = f;
  return (u16)((c.u + 0x7FFFu + ((c.u >> 16) & 1u)) >> 16);
}
DEV f32x4 mfma16(bf16x8 a, bf16x8 b, f32x4 c) {
  return __builtin_amdgcn_mfma_f32_16x16x32_bf16(a, b, c, 0, 0, 0);
}
DEV float wave_sum(float v) {
#pragma unroll
  for (int off = 32; off > 0; off >>= 1) v += __shfl_xor(v, off, 64);
  return v;
}
DEV float sum16(float v) {
  v += __shfl_xor(v, 1, 64);
  v += __shfl_xor(v, 2, 64);
  v += __shfl_xor(v, 4, 64);
  v += __shfl_xor(v, 8, 64);
  return v;
}

// ---------------------------------------------------------------------------
// INIT: slots copy; bf16 conversion of Wq / w_ih / w_hh / W1 / W2 / Wv;
// Wk transposed -> wktb (bf16).
// ---------------------------------------------------------------------------
__global__ void __launch_bounds__(256) init_prep(
    const float* __restrict__ Wk, const float* __restrict__ Wv,
    const float* __restrict__ slots_init,
    const float* __restrict__ Wq, const float* __restrict__ w_ih,
    const float* __restrict__ w_hh, const float* __restrict__ W1,
    const float* __restrict__ W2,
    float* __restrict__ slots,
    u16* __restrict__ wqb, u16* __restrict__ wihb, u16* __restrict__ whhb,
    u16* __restrict__ w1b, u16* __restrict__ w2b,
    u16* __restrict__ wvb, u16* __restrict__ wktb) {
  const int blk = blockIdx.x;
  const int tid = threadIdx.x;
  if (blk < 128) {
    const int idx = blk * 1024 + tid * 4;
    *(float4*)(slots + idx) = *(const float4*)(slots_init + idx);
  } else if (blk < 1152) {
    const int i = (blk - 128) * 1024 + tid * 4;
    const float* src; u16* dst; int off;
    if (i < 65536)       { src = Wq;   dst = wqb;  off = i; }
    else if (i < 262144) { src = w_ih; dst = wihb; off = i - 65536; }
    else if (i < 458752) { src = w_hh; dst = whhb; off = i - 262144; }
    else if (i < 720896) { src = W1;   dst = w1b;  off = i - 458752; }
    else if (i < 983040) { src = W2;   dst = w2b;  off = i - 720896; }
    else                 { src = Wv;   dst = wvb;  off = i - 983040; }
    float4 v = *(const float4*)(src + off);
    *(ushort4*)(dst + off) = make_ushort4(f2bf(v.x), f2bf(v.y), f2bf(v.z), f2bf(v.w));
  } else {
    // 64x64 tile transpose of Wk into wktb (wktb[x][y] = Wk[y][x])
    __shared__ u16 tl[64][66];
    const int tb = blk - 1152;          // 0..15
    const int r0 = (tb >> 2) * 64;
    const int c0 = (tb & 3) * 64;
    const int r = tid >> 2;
    const int cseg = (tid & 3) * 16;
#pragma unroll
    for (int q = 0; q < 4; q++) {
      float4 v = *(const float4*)(Wk + (size_t)(r0 + r) * 256 + c0 + cseg + q * 4);
      tl[r][cseg + q * 4 + 0] = f2bf(v.x);
      tl[r][cseg + q * 4 + 1] = f2bf(v.y);
      tl[r][cseg + q * 4 + 2] = f2bf(v.z);
      tl[r][cseg + q * 4 + 3] = f2bf(v.w);
    }
    __syncthreads();
    const int c = tid >> 2;
    const int rseg = (tid & 3) * 16;
    u16 out[16];
#pragma unroll
    for (int j = 0; j < 16; j++) out[j] = tl[rseg + j][c];
#pragma unroll
    for (int q = 0; q < 4; q++)
      *(ushort4*)(wktb + (size_t)(c0 + c) * 256 + r0 + rseg + q * 4) =
          make_ushort4(out[q * 4], out[q * 4 + 1], out[q * 4 + 2], out[q * 4 + 3]);
  }
}

// ---------------------------------------------------------------------------
// LN_FEAT: pure streaming LayerNorm of features -> bf16 fbuf [b][n][d].
// ---------------------------------------------------------------------------
__global__ void __launch_bounds__(256) ln_feat(
    const float* __restrict__ feat, const float* __restrict__ g,
    const float* __restrict__ bia, u16* __restrict__ fbuf) {
  const int tid = threadIdx.x;
  const int M0 = blockIdx.x * 64;
#pragma unroll 2
  for (int i = 0; i < 8; i++) {
    const int gr = i * 256 + tid;
    const int m = gr >> 5;   // row 0..63 (32 consecutive threads per row)
    const int kc = gr & 31;  // 16B-of-bf16 chunk (8 floats)
    const float* fp = feat + (size_t)(M0 + m) * 256 + kc * 8;
    float4 a0 = *(const float4*)fp;
    float4 a1 = *(const float4*)(fp + 4);
    float t1 = a0.x + a0.y + a0.z + a0.w + a1.x + a1.y + a1.z + a1.w;
    float t2 = a0.x * a0.x + a0.y * a0.y + a0.z * a0.z + a0.w * a0.w +
               a1.x * a1.x + a1.y * a1.y + a1.z * a1.z + a1.w * a1.w;
    t1 += __shfl_xor(t1, 1, 64);  t2 += __shfl_xor(t2, 1, 64);
    t1 += __shfl_xor(t1, 2, 64);  t2 += __shfl_xor(t2, 2, 64);
    t1 += __shfl_xor(t1, 4, 64);  t2 += __shfl_xor(t2, 4, 64);
    t1 += __shfl_xor(t1, 8, 64);  t2 += __shfl_xor(t2, 8, 64);
    t1 += __shfl_xor(t1, 16, 64); t2 += __shfl_xor(t2, 16, 64);
    const float mu = t1 * (1.f / 256.f);
    const float rs = rsqrtf(t2 * (1.f / 256.f) - mu * mu + 1e-5f);
    float4 g0 = *(const float4*)(g + kc * 8);
    float4 g1 = *(const float4*)(g + kc * 8 + 4);
    float4 b0 = *(const float4*)(bia + kc * 8);
    float4 b1 = *(const float4*)(bia + kc * 8 + 4);
    u16 y[8];
    y[0] = f2bf((a0.x - mu) * rs * g0.x + b0.x);
    y[1] = f2bf((a0.y - mu) * rs * g0.y + b0.y);
    y[2] = f2bf((a0.z - mu) * rs * g0.z + b0.z);
    y[3] = f2bf((a0.w - mu) * rs * g0.w + b0.w);
    y[4] = f2bf((a1.x - mu) * rs * g1.x + b1.x);
    y[5] = f2bf((a1.y - mu) * rs * g1.y + b1.y);
    y[6] = f2bf((a1.z - mu) * rs * g1.z + b1.z);
    y[7] = f2bf((a1.w - mu) * rs * g1.w + b1.w);
    uint4 pk = make_uint4((u32)y[0] | ((u32)y[1] << 16), (u32)y[2] | ((u32)y[3] << 16),
                          (u32)y[4] | ((u32)y[5] << 16), (u32)y[6] | ((u32)y[7] << 16));
    *(uint4*)(fbuf + (size_t)(M0 + m) * 256 + kc * 8) = pk;
  }
}

// ---------------------------------------------------------------------------
// QK: per-batch: LN(slots) -> q = ln@Wq^T -> qk = q@Wk -> qkbuf bf16
// qkbuf [b][16][256], rows 8-15 zero.
// ---------------------------------------------------------------------------
__global__ void __launch_bounds__(256) slot_qk(
    const float* __restrict__ slots, const float* __restrict__ gs, const float* __restrict__ bs,
    const u16* __restrict__ wqb, const u16* __restrict__ wktb,
    u16* __restrict__ qkbuf) {
  __shared__ u16 lnb[16 * 264];
  __shared__ u16 qld[16 * 264];
  const int b = blockIdx.x;
  const int tid = threadIdx.x;
  const int lane = tid & 63;
  const int wv = tid >> 6;
  const int cl = lane & 15;
  const int rq = lane >> 4;
  const f32x4 Z = {0.f, 0.f, 0.f, 0.f};

  for (int i = tid; i < 8 * 264; i += 256) lnb[8 * 264 + i] = 0;

  for (int rr = 0; rr < 2; rr++) {
    const int s = wv * 2 + rr;
    float4 x4 = *(const float4*)(slots + ((size_t)b * 8 + s) * 256 + lane * 4);
    float x[4] = {x4.x, x4.y, x4.z, x4.w};
    float s1 = x[0] + x[1] + x[2] + x[3];
    float s2 = x[0] * x[0] + x[1] * x[1] + x[2] * x[2] + x[3] * x[3];
    s1 = wave_sum(s1);
    s2 = wave_sum(s2);
    float mu = s1 * (1.f / 256.f);
    float rstd = rsqrtf(s2 * (1.f / 256.f) - mu * mu + 1e-5f);
    float4 g4 = *(const float4*)(gs + lane * 4);
    float4 b4 = *(const float4*)(bs + lane * 4);
    u16 o4[4];
    o4[0] = f2bf((x[0] - mu) * rstd * g4.x + b4.x);
    o4[1] = f2bf((x[1] - mu) * rstd * g4.y + b4.y);
    o4[2] = f2bf((x[2] - mu) * rstd * g4.z + b4.z);
    o4[3] = f2bf((x[3] - mu) * rstd * g4.w + b4.w);
    *(ushort4*)&lnb[s * 264 + lane * 4] = make_ushort4(o4[0], o4[1], o4[2], o4[3]);
  }
  __syncthreads();

  // q = lnb @ Wq^T -> qld
  {
    bf16x8 af[8];
#pragma unroll
    for (int ks = 0; ks < 8; ks++)
      af[ks] = *(const bf16x8*)&lnb[cl * 264 + ks * 32 + rq * 8];
#pragma unroll
    for (int t = 0; t < 4; t++) {
      const int of = wv * 64 + t * 16;
      f32x4 acc = Z;
#pragma unroll
      for (int ks = 0; ks < 8; ks++) {
        bf16x8 bw = *(const bf16x8*)(wqb + (size_t)(of + cl) * 256 + ks * 32 + rq * 8);
        acc = mfma16(af[ks], bw, acc);
      }
#pragma unroll
      for (int r = 0; r < 4; r++)
        qld[(rq * 4 + r) * 264 + of + cl] = f2bf(acc[r]);
    }
  }
  __syncthreads();

  // qk = q @ Wk -> qkbuf (global, bf16)
  {
    bf16x8 a2[8];
#pragma unroll
    for (int ks = 0; ks < 8; ks++)
      a2[ks] = *(const bf16x8*)&qld[cl * 264 + ks * 32 + rq * 8];
#pragma unroll
    for (int t = 0; t < 4; t++) {
      const int of = wv * 64 + t * 16;
      f32x4 acc = Z;
#pragma unroll
      for (int ks = 0; ks < 8; ks++) {
        bf16x8 bw = *(const bf16x8*)(wktb + (size_t)(of + cl) * 256 + ks * 32 + rq * 8);
        acc = mfma16(a2[ks], bw, acc);
      }
#pragma unroll
      for (int r = 0; r < 4; r++)
        qkbuf[(size_t)b * 4096 + (rq * 4 + r) * 256 + of + cl] = f2bf(acc[r]);
    }
  }
}

// ---------------------------------------------------------------------------
// P: attention pass over a 64-n chunk. f-tile staged ONCE into LDS
// (XOR-swizzled), used for QK^T (row reads) and P·V (column reads).
//   logits = qk @ f^T -> softmax(slots) -> P -> Pf partial into part_acc.
// ---------------------------------------------------------------------------
__global__ void __launch_bounds__(256) attn_pass(
    const u16* __restrict__ qkbuf, const u16* __restrict__ fbuf,
    float* __restrict__ part_acc, float* __restrict__ part_den,
    float* __restrict__ attn_out, int store_attn) {
  __shared__ u16 Asm[64 * 264];  // 33 KB f-tile, swizzled 16B chunks
  __shared__ u16 pt[16 * 72];    // P tile (bf16), rows 8-15 garbage (discarded)
  const int chunk = blockIdx.x;  // 0..63
  const int b = blockIdx.y;      // 0..63
  const int n0 = chunk * 64;
  const int tid = threadIdx.x;
  const int lane = tid & 63;
  const int wv = tid >> 6;
  const int cl = lane & 15;
  const int rq = lane >> 4;
  const f32x4 Z = {0.f, 0.f, 0.f, 0.f};

  // ---- stage f-tile [64 n][256 d] bf16 -> LDS, swizzled ----
  const u16* fsrc = fbuf + ((size_t)b * 4096 + n0) * 256;
#pragma unroll
  for (int i = 0; i < 8; i++) {
    const int gr = i * 256 + tid;
    const int m = gr >> 5;   // n-local 0..63
    const int kc = gr & 31;  // 16B chunk (8 bf16 of d)
    uint4 v = *(const uint4*)(fsrc + (size_t)m * 256 + kc * 8);
    const int sw = (kc & 24) | ((kc & 7) ^ (m & 7) ^ ((m >> 3) & 7));
    *(uint4*)&Asm[m * 264 + sw * 8] = v;
  }

  // qk fragments (overlap with staging)
  bf16x8 aq[8];
#pragma unroll
  for (int ks = 0; ks < 8; ks++)
    aq[ks] = *(const bf16x8*)(qkbuf + (size_t)b * 4096 + cl * 256 + ks * 32 + rq * 8);
  __syncthreads();

  // ---- QK^T + softmax over slots ----
  {
    const int nl = wv * 16;
    const int n = nl + cl;
    f32x4 acc = Z;
#pragma unroll
    for (int ks = 0; ks < 8; ks++) {
      const int c = ks * 4 + rq;
      const int ca = (c & 24) | ((c & 7) ^ (n & 7) ^ ((n >> 3) & 7));
      bf16x8 bk = *(const bf16x8*)&Asm[n * 264 + ca * 8];
      acc = mfma16(aq[ks], bk, acc);
    }
    float l[4];
#pragma unroll
    for (int r = 0; r < 4; r++) l[r] = acc[r] * 0.0625f;
    float m4 = fmaxf(fmaxf(l[0], l[1]), fmaxf(l[2], l[3]));
    float m8 = fmaxf(m4, __shfl_xor(m4, 16, 64));
    float e[4];
    float s4 = 0.f;
#pragma unroll
    for (int r = 0; r < 4; r++) { e[r] = __expf(l[r] - m8); s4 += e[r]; }
    float s8 = s4 + __shfl_xor(s4, 16, 64);
    float inv = 1.f / s8;
    float pa[4];
#pragma unroll
    for (int r = 0; r < 4; r++) pa[r] = e[r] * inv + 1e-8f;
#pragma unroll
    for (int r = 0; r < 4; r++) pt[(rq * 4 + r) * 72 + nl + cl] = f2bf(pa[r]);
    if (store_attn && lane < 32) {
#pragma unroll
      for (int r = 0; r < 4; r++)
        attn_out[((size_t)b * 8 + rq * 4 + r) * 4096 + n0 + nl + cl] = pa[r];
    }
    float dacc[4];
#pragma unroll
    for (int r = 0; r < 4; r++) dacc[r] = sum16(pa[r]);
    if (cl == 0 && lane < 32) {
#pragma unroll
      for (int r = 0; r < 4; r++)
        part_den[(((size_t)b * 64 + chunk) * 4 + wv) * 8 + rq * 4 + r] = dacc[r];
    }
  }
  __syncthreads();

  // ---- P·V: B-fragments are COLUMNS of the LDS f-tile ----
#pragma unroll
  for (int t = 0; t < 4; t++) {
    const int d = wv * 64 + t * 16 + cl;
    const int dchunk = d >> 3;
    const int doff = d & 7;
    f32x4 acc = Z;
#pragma unroll
    for (int ks = 0; ks < 2; ks++) {
      const int r0 = ks * 32 + rq * 8;
      const int cx = (ks * 4 + rq) & 7;
      union { u16 w[8]; bf16x8 v; } bv;
#pragma unroll
      for (int j = 0; j < 8; j++) {
        const int ca = (dchunk & 24) | ((dchunk & 7) ^ j ^ cx);
        bv.w[j] = Asm[(r0 + j) * 264 + ca * 8 + doff];
      }
      bf16x8 pa8 = *(const bf16x8*)&pt[cl * 72 + r0];
      acc = mfma16(pa8, bv.v, acc);
    }
    if (lane < 32) {
#pragma unroll
      for (int r = 0; r < 4; r++)
        part_acc[(((size_t)b * 64 + chunk) * 8 + rq * 4 + r) * 256 + d] = acc[r];
    }
  }
}

// ---------------------------------------------------------------------------
// U: reduce partials -> Pf_norm; updates = Pf_norm @ Wv^T; GRU; LN; MLP; res.
// ---------------------------------------------------------------------------
__global__ void __launch_bounds__(256) slot_update(
    const float* __restrict__ part_acc, const float* __restrict__ part_den,
    float* __restrict__ slots,
    const u16* __restrict__ wihb, const u16* __restrict__ whhb,
    const float* __restrict__ b_ih, const float* __restrict__ b_hh,
    const float* __restrict__ gm, const float* __restrict__ bm,
    const u16* __restrict__ w1b, const float* __restrict__ b1,
    const u16* __restrict__ w2b, const float* __restrict__ b2,
    const u16* __restrict__ wvb,
    float* __restrict__ slots_out, int last) {
  __shared__ u16 ubf[16 * 264];
  __shared__ u16 hbf[16 * 264];
  __shared__ u16 updbf[16 * 264];
  __shared__ float hf32[8 * 256];
  __shared__ float midf[8 * 256];
  __shared__ u16 h1bf[16 * 1032];
  __shared__ float denp[64];
  __shared__ float denl[8];
  const int b = blockIdx.x;
  const int tid = threadIdx.x;
  const int lane = tid & 63;
  const int wv = tid >> 6;
  const int cl = lane & 15;
  const int rq = lane >> 4;
  const f32x4 Z = {0.f, 0.f, 0.f, 0.f};

  for (int i = tid; i < 8 * 264; i += 256) { ubf[8 * 264 + i] = 0; hbf[8 * 264 + i] = 0; }
  if (tid < 64) {
    const int s = tid & 7, g = tid >> 3;  // g = 0..7
    float sum = 0.f;
    for (int e = g * 32; e < g * 32 + 32; e++)
      sum += part_den[((size_t)b * 256 + e) * 8 + s];
    denp[tid] = sum;
  }
  __syncthreads();
  if (tid < 8) {
    float s2 = 0.f;
    for (int g = 0; g < 8; g++) s2 += denp[g * 8 + tid];
    denl[tid] = s2;
  }
  __syncthreads();

#pragma unroll
  for (int i = 0; i < 8; i++) {
    float s = 0.f;
#pragma unroll 8
    for (int c = 0; c < 64; c++)
      s += part_acc[(((size_t)b * 64 + c) * 8 + i) * 256 + tid];
    float u = s / denl[i];
    ubf[i * 264 + tid] = f2bf(u);          // Pf_norm (attn_wm @ f_ln)
    float h = slots[((size_t)b * 8 + i) * 256 + tid];
    hf32[i * 256 + tid] = h;
    hbf[i * 264 + tid] = f2bf(h);
  }
  __syncthreads();

  // ---- updates = Pf_norm @ Wv^T -> updbf ----
  {
    bf16x8 apf[8];
#pragma unroll
    for (int ks = 0; ks < 8; ks++)
      apf[ks] = *(const bf16x8*)&ubf[cl * 264 + ks * 32 + rq * 8];
#pragma unroll
    for (int t = 0; t < 4; t++) {
      const int of = wv * 64 + t * 16;
      f32x4 acc = Z;
#pragma unroll
      for (int ks = 0; ks < 8; ks++) {
        bf16x8 bw = *(const bf16x8*)(wvb + (size_t)(of + cl) * 256 + ks * 32 + rq * 8);
        acc = mfma16(apf[ks], bw, acc);
      }
#pragma unroll
      for (int r = 0; r < 4; r++)
        updbf[(rq * 4 + r) * 264 + of + cl] = f2bf(acc[r]);
    }
  }
  __syncthreads();

  // ---- GRU ----
  bf16x8 au[8], ah[8];
#pragma unroll
  for (int ks = 0; ks < 8; ks++) {
    au[ks] = *(const bf16x8*)&updbf[cl * 264 + ks * 32 + rq * 8];
    ah[ks] = *(const bf16x8*)&hbf[cl * 264 + ks * 32 + rq * 8];
  }
#pragma unroll
  for (int j4 = 0; j4 < 4; j4++) {
    const int j = wv * 4 + j4;  // o-tile 0..15
    f32x4 a_ir = Z, a_iz = Z, a_in = Z, a_hr = Z, a_hz = Z, a_hn = Z;
#pragma unroll
    for (int ks = 0; ks < 8; ks++) {
      const int koff = ks * 32 + rq * 8;
      const int o_r = j * 16 + cl;
      bf16x8 bri = *(const bf16x8*)(wihb + (size_t)o_r * 256 + koff);
      bf16x8 bzi = *(const bf16x8*)(wihb + (size_t)(256 + o_r) * 256 + koff);
      bf16x8 bni = *(const bf16x8*)(wihb + (size_t)(512 + o_r) * 256 + koff);
      bf16x8 brh = *(const bf16x8*)(whhb + (size_t)o_r * 256 + koff);
      bf16x8 bzh = *(const bf16x8*)(whhb + (size_t)(256 + o_r) * 256 + koff);
      bf16x8 bnh = *(const bf16x8*)(whhb + (size_t)(512 + o_r) * 256 + koff);
      a_ir = mfma16(au[ks], bri, a_ir);
      a_iz = mfma16(au[ks], bzi, a_iz);
      a_in = mfma16(au[ks], bni, a_in);
      a_hr = mfma16(ah[ks], brh, a_hr);
      a_hz = mfma16(ah[ks], bzh, a_hz);
      a_hn = mfma16(ah[ks], bnh, a_hn);
    }
    if (lane < 32) {
      const int d = j * 16 + cl;
      const float bihr = b_ih[d], bihz = b_ih[256 + d], bihn = b_ih[512 + d];
      const float bhhr = b_hh[d], bhhz = b_hh[256 + d], bhhn = b_hh[512 + d];
#pragma unroll
      for (int r = 0; r < 4; r++) {
        const int s = rq * 4 + r;
        float ir = a_ir[r] + bihr, iz = a_iz[r] + bihz, inn = a_in[r] + bihn;
        float hr = a_hr[r] + bhhr, hz = a_hz[r] + bhhz, hn = a_hn[r] + bhhn;
        float rg = 1.f / (1.f + __expf(-(ir + hr)));
        float zg = 1.f / (1.f + __expf(-(iz + hz)));
        float ng = tanhf(inn + rg * hn);
        float h = hf32[s * 256 + d];
        midf[s * 256 + d] = (1.f - zg) * ng + zg * h;
      }
    }
  }
  __syncthreads();

  // ---- LN (g_mlp,b_mlp) of midf -> ubf (rows 8-15 still zero) ----
  for (int rr = 0; rr < 2; rr++) {
    const int s = wv * 2 + rr;
    float4 x4 = *(const float4*)&midf[s * 256 + lane * 4];
    float x[4] = {x4.x, x4.y, x4.z, x4.w};
    float s1 = x[0] + x[1] + x[2] + x[3];
    float s2 = x[0] * x[0] + x[1] * x[1] + x[2] * x[2] + x[3] * x[3];
    s1 = wave_sum(s1);
    s2 = wave_sum(s2);
    float mu = s1 * (1.f / 256.f);
    float rstd = rsqrtf(s2 * (1.f / 256.f) - mu * mu + 1e-5f);
    float4 g4 = *(const float4*)(gm + lane * 4);
    float4 b4 = *(const float4*)(bm + lane * 4);
    u16 o4[4];
    o4[0] = f2bf((x[0] - mu) * rstd * g4.x + b4.x);
    o4[1] = f2bf((x[1] - mu) * rstd * g4.y + b4.y);
    o4[2] = f2bf((x[2] - mu) * rstd * g4.z + b4.z);
    o4[3] = f2bf((x[3] - mu) * rstd * g4.w + b4.w);
    *(ushort4*)&ubf[s * 264 + lane * 4] = make_ushort4(o4[0], o4[1], o4[2], o4[3]);
  }
  __syncthreads();

  // ---- MLP1: relu(ln @ W1^T + b1) -> h1bf ----
  bf16x8 al[8];
#pragma unroll
  for (int ks = 0; ks < 8; ks++)
    al[ks] = *(const bf16x8*)&ubf[cl * 264 + ks * 32 + rq * 8];
#pragma unroll
  for (int t = 0; t < 16; t++) {
    const int of = wv * 256 + t * 16;
    f32x4 acc = Z;
#pragma unroll
    for (int ks = 0; ks < 8; ks++) {
      bf16x8 bw = *(const bf16x8*)(w1b + (size_t)(of + cl) * 256 + ks * 32 + rq * 8);
      acc = mfma16(al[ks], bw, acc);
    }
    const float bb = b1[of + cl];
#pragma unroll
    for (int r = 0; r < 4; r++)
      h1bf[(rq * 4 + r) * 1032 + of + cl] = f2bf(fmaxf(acc[r] + bb, 0.f));
  }
  __syncthreads();

  // ---- MLP2: mid + h1 @ W2^T + b2 -> slots (and out on last iter) ----
  f32x4 acc2[4] = {Z, Z, Z, Z};
  for (int ks = 0; ks < 32; ks++) {
    bf16x8 ah1 = *(const bf16x8*)&h1bf[cl * 1032 + ks * 32 + rq * 8];
#pragma unroll
    for (int t = 0; t < 4; t++) {
      const int o = wv * 64 + t * 16 + cl;
      bf16x8 bw = *(const bf16x8*)(w2b + (size_t)o * 1024 + ks * 32 + rq * 8);
      acc2[t] = mfma16(ah1, bw, acc2[t]);
    }
  }
  if (lane < 32) {
#pragma unroll
    for (int t = 0; t < 4; t++) {
      const int o = wv * 64 + t * 16 + cl;
      const float bb = b2[o];
#pragma unroll
      for (int r = 0; r < 4; r++) {
        const int s = rq * 4 + r;
        float val = midf[s * 256 + o] + acc2[t][r] + bb;
        slots[((size_t)b * 8 + s) * 256 + o] = val;
        if (last) slots_out[((size_t)b * 8 + s) * 256 + o] = val;
      }
    }
  }
}

// ---------------------------------------------------------------------------
extern "C" void kernel_launch(void* const* d_in, const int* in_sizes, int n_in,
                              void* d_out, int out_size, void* d_ws, size_t ws_size,
                              hipStream_t stream) {
  (void)in_sizes; (void)n_in; (void)out_size;
  const float* features = (const float*)d_in[0];
  const float* slots_init = (const float*)d_in[1];
  const float* g_feat = (const float*)d_in[2];
  const float* b_feat = (const float*)d_in[3];
  const float* g_slots = (const float*)d_in[4];
  const float* b_slots = (const float*)d_in[5];
  const float* g_mlp = (const float*)d_in[6];
  const float* b_mlp = (const float*)d_in[7];
  const float* Wk = (const float*)d_in[8];
  const float* Wv = (const float*)d_in[9];
  const float* Wq = (const float*)d_in[10];
  const float* w_ih = (const float*)d_in[11];
  const float* w_hh = (const float*)d_in[12];
  const float* b_ih = (const float*)d_in[13];
  const float* b_hh = (const float*)d_in[14];
  const float* W1 = (const float*)d_in[15];
  const float* b1 = (const float*)d_in[16];
  const float* W2 = (const float*)d_in[17];
  const float* b2 = (const float*)d_in[18];

  // Workspace layout (bytes). Total = 171,573,248 (L3-resident working set).
  const size_t REQUIRED = 171573248ull;
  if (ws_size < REQUIRED) return;

  char* ws = (char*)d_ws;
  u16* fbuf = (u16*)(ws + 0);                  // 134,217,728  LN(feat) [b][n][d]
  float* part_acc = (float*)(ws + 134217728);  // 33,554,432   [b][64][8][256]
  float* part_den = (float*)(ws + 167772160);  // 524,288      [b][64][4][8]
  u16* qkbuf = (u16*)(ws + 168296448);         // 524,288      [b][16][256]
  float* slots = (float*)(ws + 168820736);     // 524,288
  u16* wktb = (u16*)(ws + 169345024);          // 131,072  Wk^T bf16
  u16* wvb = (u16*)(ws + 169476096);           // 131,072  Wv bf16
  u16* wqb = (u16*)(ws + 169607168);           // 131,072
  u16* wihb = (u16*)(ws + 169738240);          // 393,216
  u16* whhb = (u16*)(ws + 170131456);          // 393,216
  u16* w1b = (u16*)(ws + 170524672);           // 524,288
  u16* w2b = (u16*)(ws + 171048960);           // 524,288

  float* out_slots = (float*)d_out;
  float* out_attn = out_slots + 131072;

  init_prep<<<1168, 256, 0, stream>>>(Wk, Wv, slots_init, Wq, w_ih, w_hh, W1, W2,
                                      slots, wqb, wihb, whhb, w1b, w2b, wvb, wktb);
  ln_feat<<<4096, 256, 0, stream>>>(features, g_feat, b_feat, fbuf);
  for (int it = 0; it < 3; it++) {
    slot_qk<<<64, 256, 0, stream>>>(slots, g_slots, b_slots, wqb, wktb, qkbuf);
    attn_pass<<<dim3(64, 64), 256, 0, stream>>>(qkbuf, fbuf, part_acc, part_den,
                                                out_attn, it == 2 ? 1 : 0);
    slot_update<<<64, 256, 0, stream>>>(part_acc, part_den, slots, wihb, whhb, b_ih, b_hh,
                                        g_mlp, b_mlp, w1b, b1, w2b, b2, wvb,
                                        out_slots, it == 2 ? 1 : 0);
  }
}

// Round 5
// 830.180 us; speedup vs baseline: 1.1359x; 1.0088x over previous
//
#include <hip/hip_runtime.h>
#include <stdint.h>

typedef unsigned short u16;
typedef unsigned int u32;
typedef __bf16 bf16_t;
typedef bf16_t bf16x8 __attribute__((ext_vector_type(8)));
typedef float f32x4 __attribute__((ext_vector_type(4)));

#define DEV static __device__ __forceinline__

DEV float bf2f(u16 a) {
  union { u32 u; float f; } c; c.u = ((u32)a) << 16; return c.f;
}
DEV u16 f2bf(float f) {
  union { float f; u32 u; } c; c.f = f;
  return (u16)((c.u + 0x7FFFu + ((c.u >> 16) & 1u)) >> 16);
}
DEV f32x4 mfma16(bf16x8 a, bf16x8 b, f32x4 c) {
  return __builtin_amdgcn_mfma_f32_16x16x32_bf16(a, b, c, 0, 0, 0);
}
DEV float wave_sum(float v) {
#pragma unroll
  for (int off = 32; off > 0; off >>= 1) v += __shfl_xor(v, off, 64);
  return v;
}
DEV float sum16(float v) {
  v += __shfl_xor(v, 1, 64);
  v += __shfl_xor(v, 2, 64);
  v += __shfl_xor(v, 4, 64);
  v += __shfl_xor(v, 8, 64);
  return v;
}

// ---------------------------------------------------------------------------
// INIT: slots copy; bf16 conversion of Wq / w_ih / w_hh / W1 / W2 / Wv;
// Wk transposed -> wktb (bf16).
// ---------------------------------------------------------------------------
__global__ void __launch_bounds__(256) init_prep(
    const float* __restrict__ Wk, const float* __restrict__ Wv,
    const float* __restrict__ slots_init,
    const float* __restrict__ Wq, const float* __restrict__ w_ih,
    const float* __restrict__ w_hh, const float* __restrict__ W1,
    const float* __restrict__ W2,
    float* __restrict__ slots,
    u16* __restrict__ wqb, u16* __restrict__ wihb, u16* __restrict__ whhb,
    u16* __restrict__ w1b, u16* __restrict__ w2b,
    u16* __restrict__ wvb, u16* __restrict__ wktb) {
  const int blk = blockIdx.x;
  const int tid = threadIdx.x;
  if (blk < 128) {
    const int idx = blk * 1024 + tid * 4;
    *(float4*)(slots + idx) = *(const float4*)(slots_init + idx);
  } else if (blk < 1152) {
    const int i = (blk - 128) * 1024 + tid * 4;
    const float* src; u16* dst; int off;
    if (i < 65536)       { src = Wq;   dst = wqb;  off = i; }
    else if (i < 262144) { src = w_ih; dst = wihb; off = i - 65536; }
    else if (i < 458752) { src = w_hh; dst = whhb; off = i - 262144; }
    else if (i < 720896) { src = W1;   dst = w1b;  off = i - 458752; }
    else if (i < 983040) { src = W2;   dst = w2b;  off = i - 720896; }
    else                 { src = Wv;   dst = wvb;  off = i - 983040; }
    float4 v = *(const float4*)(src + off);
    *(ushort4*)(dst + off) = make_ushort4(f2bf(v.x), f2bf(v.y), f2bf(v.z), f2bf(v.w));
  } else {
    // 64x64 tile transpose of Wk into wktb (wktb[x][y] = Wk[y][x])
    __shared__ u16 tl[64][66];
    const int tb = blk - 1152;          // 0..15
    const int r0 = (tb >> 2) * 64;
    const int c0 = (tb & 3) * 64;
    const int r = tid >> 2;
    const int cseg = (tid & 3) * 16;
#pragma unroll
    for (int q = 0; q < 4; q++) {
      float4 v = *(const float4*)(Wk + (size_t)(r0 + r) * 256 + c0 + cseg + q * 4);
      tl[r][cseg + q * 4 + 0] = f2bf(v.x);
      tl[r][cseg + q * 4 + 1] = f2bf(v.y);
      tl[r][cseg + q * 4 + 2] = f2bf(v.z);
      tl[r][cseg + q * 4 + 3] = f2bf(v.w);
    }
    __syncthreads();
    const int c = tid >> 2;
    const int rseg = (tid & 3) * 16;
    u16 out[16];
#pragma unroll
    for (int j = 0; j < 16; j++) out[j] = tl[rseg + j][c];
#pragma unroll
    for (int q = 0; q < 4; q++)
      *(ushort4*)(wktb + (size_t)(c0 + c) * 256 + r0 + rseg + q * 4) =
          make_ushort4(out[q * 4], out[q * 4 + 1], out[q * 4 + 2], out[q * 4 + 3]);
  }
}

// ---------------------------------------------------------------------------
// LN_FEAT: streaming LayerNorm of features (g,b applied) -> bf16, stored
// both as fbuf [b][n][d] and fbuf_t [b][d][n]. 64-row tiles. (round-3 body)
// ---------------------------------------------------------------------------
__global__ void __launch_bounds__(256) ln_feat(
    const float* __restrict__ feat, const float* __restrict__ g,
    const float* __restrict__ bia,
    u16* __restrict__ fbuf, u16* __restrict__ fbuf_t) {
  __shared__ u16 T[64 * 264];  // 33 KB, row pitch 264 u16
  const int tid = threadIdx.x;
  const int M0 = blockIdx.x * 64;
  const int b = M0 >> 12;
  const int nb = M0 & 4095;

  // ---- phase A: load fp32, LN per row, write fbuf rows + LDS tile ----
#pragma unroll 2
  for (int i = 0; i < 8; i++) {
    const int gr = i * 256 + tid;
    const int m = gr >> 5;   // row 0..63 (32 consecutive threads per row)
    const int kc = gr & 31;  // 16B-of-bf16 chunk (8 floats)
    const float* fp = feat + (size_t)(M0 + m) * 256 + kc * 8;
    float4 a0 = *(const float4*)fp;
    float4 a1 = *(const float4*)(fp + 4);
    float t1 = a0.x + a0.y + a0.z + a0.w + a1.x + a1.y + a1.z + a1.w;
    float t2 = a0.x * a0.x + a0.y * a0.y + a0.z * a0.z + a0.w * a0.w +
               a1.x * a1.x + a1.y * a1.y + a1.z * a1.z + a1.w * a1.w;
    t1 += __shfl_xor(t1, 1, 64);  t2 += __shfl_xor(t2, 1, 64);
    t1 += __shfl_xor(t1, 2, 64);  t2 += __shfl_xor(t2, 2, 64);
    t1 += __shfl_xor(t1, 4, 64);  t2 += __shfl_xor(t2, 4, 64);
    t1 += __shfl_xor(t1, 8, 64);  t2 += __shfl_xor(t2, 8, 64);
    t1 += __shfl_xor(t1, 16, 64); t2 += __shfl_xor(t2, 16, 64);
    const float mu = t1 * (1.f / 256.f);
    const float rs = rsqrtf(t2 * (1.f / 256.f) - mu * mu + 1e-5f);
    float4 g0 = *(const float4*)(g + kc * 8);
    float4 g1 = *(const float4*)(g + kc * 8 + 4);
    float4 b0 = *(const float4*)(bia + kc * 8);
    float4 b1 = *(const float4*)(bia + kc * 8 + 4);
    u16 y[8];
    y[0] = f2bf((a0.x - mu) * rs * g0.x + b0.x);
    y[1] = f2bf((a0.y - mu) * rs * g0.y + b0.y);
    y[2] = f2bf((a0.z - mu) * rs * g0.z + b0.z);
    y[3] = f2bf((a0.w - mu) * rs * g0.w + b0.w);
    y[4] = f2bf((a1.x - mu) * rs * g1.x + b1.x);
    y[5] = f2bf((a1.y - mu) * rs * g1.y + b1.y);
    y[6] = f2bf((a1.z - mu) * rs * g1.z + b1.z);
    y[7] = f2bf((a1.w - mu) * rs * g1.w + b1.w);
    uint4 pk = make_uint4((u32)y[0] | ((u32)y[1] << 16), (u32)y[2] | ((u32)y[3] << 16),
                          (u32)y[4] | ((u32)y[5] << 16), (u32)y[6] | ((u32)y[7] << 16));
    *(uint4*)&T[m * 264 + kc * 8] = pk;
    *(uint4*)(fbuf + (size_t)(M0 + m) * 256 + kc * 8) = pk;
  }
  __syncthreads();

  // ---- phase C: transposed write fbuf_t [b][d][n] ----
  const int dl = tid >> 4;        // 0..15
  const int ns4 = (tid & 15) * 4; // n-local 0..60
#pragma unroll 4
  for (int o = 0; o < 16; o++) {
    const int d = dl + o * 16;
    u16 v0 = T[(ns4 + 0) * 264 + d];
    u16 v1 = T[(ns4 + 1) * 264 + d];
    u16 v2 = T[(ns4 + 2) * 264 + d];
    u16 v3 = T[(ns4 + 3) * 264 + d];
    *(ushort4*)(fbuf_t + ((size_t)b * 256 + d) * 4096 + nb + ns4) = make_ushort4(v0, v1, v2, v3);
  }
}

// ---------------------------------------------------------------------------
// QK: per-batch: LN(slots) -> q = ln@Wq^T -> qk = q@Wk -> qkbuf bf16
// qkbuf [b][16][256], rows 8-15 zero. (round-4 body, proven)
// ---------------------------------------------------------------------------
__global__ void __launch_bounds__(256) slot_qk(
    const float* __restrict__ slots, const float* __restrict__ gs, const float* __restrict__ bs,
    const u16* __restrict__ wqb, const u16* __restrict__ wktb,
    u16* __restrict__ qkbuf) {
  __shared__ u16 lnb[16 * 264];
  __shared__ u16 qld[16 * 264];
  const int b = blockIdx.x;
  const int tid = threadIdx.x;
  const int lane = tid & 63;
  const int wv = tid >> 6;
  const int cl = lane & 15;
  const int rq = lane >> 4;
  const f32x4 Z = {0.f, 0.f, 0.f, 0.f};

  for (int i = tid; i < 8 * 264; i += 256) lnb[8 * 264 + i] = 0;

  for (int rr = 0; rr < 2; rr++) {
    const int s = wv * 2 + rr;
    float4 x4 = *(const float4*)(slots + ((size_t)b * 8 + s) * 256 + lane * 4);
    float x[4] = {x4.x, x4.y, x4.z, x4.w};
    float s1 = x[0] + x[1] + x[2] + x[3];
    float s2 = x[0] * x[0] + x[1] * x[1] + x[2] * x[2] + x[3] * x[3];
    s1 = wave_sum(s1);
    s2 = wave_sum(s2);
    float mu = s1 * (1.f / 256.f);
    float rstd = rsqrtf(s2 * (1.f / 256.f) - mu * mu + 1e-5f);
    float4 g4 = *(const float4*)(gs + lane * 4);
    float4 b4 = *(const float4*)(bs + lane * 4);
    u16 o4[4];
    o4[0] = f2bf((x[0] - mu) * rstd * g4.x + b4.x);
    o4[1] = f2bf((x[1] - mu) * rstd * g4.y + b4.y);
    o4[2] = f2bf((x[2] - mu) * rstd * g4.z + b4.z);
    o4[3] = f2bf((x[3] - mu) * rstd * g4.w + b4.w);
    *(ushort4*)&lnb[s * 264 + lane * 4] = make_ushort4(o4[0], o4[1], o4[2], o4[3]);
  }
  __syncthreads();

  // q = lnb @ Wq^T -> qld
  {
    bf16x8 af[8];
#pragma unroll
    for (int ks = 0; ks < 8; ks++)
      af[ks] = *(const bf16x8*)&lnb[cl * 264 + ks * 32 + rq * 8];
#pragma unroll
    for (int t = 0; t < 4; t++) {
      const int of = wv * 64 + t * 16;
      f32x4 acc = Z;
#pragma unroll
      for (int ks = 0; ks < 8; ks++) {
        bf16x8 bw = *(const bf16x8*)(wqb + (size_t)(of + cl) * 256 + ks * 32 + rq * 8);
        acc = mfma16(af[ks], bw, acc);
      }
#pragma unroll
      for (int r = 0; r < 4; r++)
        qld[(rq * 4 + r) * 264 + of + cl] = f2bf(acc[r]);
    }
  }
  __syncthreads();

  // qk = q @ Wk -> qkbuf (global, bf16)
  {
    bf16x8 a2[8];
#pragma unroll
    for (int ks = 0; ks < 8; ks++)
      a2[ks] = *(const bf16x8*)&qld[cl * 264 + ks * 32 + rq * 8];
#pragma unroll
    for (int t = 0; t < 4; t++) {
      const int of = wv * 64 + t * 16;
      f32x4 acc = Z;
#pragma unroll
      for (int ks = 0; ks < 8; ks++) {
        bf16x8 bw = *(const bf16x8*)(wktb + (size_t)(of + cl) * 256 + ks * 32 + rq * 8);
        acc = mfma16(a2[ks], bw, acc);
      }
#pragma unroll
      for (int r = 0; r < 4; r++)
        qkbuf[(size_t)b * 4096 + (rq * 4 + r) * 256 + of + cl] = f2bf(acc[r]);
    }
  }
}

// ---------------------------------------------------------------------------
// P: attention over a 256-n strip, streaming both f layouts from global
// (L3-resident). No f LDS staging, no scalar gathers.
//   QK^T:  logits[s][n] = qk[s][:] . fbuf[n][:]      (row reads)
//   PV:    outT[d][s]  = sum_n fbuf_t[d][n] P[s][n]  (row reads both operands)
// Partials (16 per batch) -> part_acc; denom partials -> part_den.
// ---------------------------------------------------------------------------
__global__ void __launch_bounds__(256, 4) attn_pass(
    const u16* __restrict__ qkbuf, const u16* __restrict__ fbuf,
    const u16* __restrict__ fbuf_t,
    float* __restrict__ part_acc, float* __restrict__ part_den,
    float* __restrict__ attn_out, int store_attn) {
  __shared__ u16 pt[8 * 264];      // P strip [8 s][256 n + pad]
  __shared__ float outp[8 * 260];  // partial out [s][d], padded pitch
  const int sub = blockIdx.x;      // 0..15
  const int b = blockIdx.y;        // 0..63
  const int n0 = sub * 256;
  const int tid = threadIdx.x;
  const int lane = tid & 63;
  const int wv = tid >> 6;
  const int cl = lane & 15;
  const int rq = lane >> 4;
  const f32x4 Z = {0.f, 0.f, 0.f, 0.f};

  // qk fragments (A operand; rows 8-15 of qkbuf are zero)
  bf16x8 aq[8];
#pragma unroll
  for (int ks = 0; ks < 8; ks++)
    aq[ks] = *(const bf16x8*)(qkbuf + (size_t)b * 4096 + cl * 256 + ks * 32 + rq * 8);

  // ---- QK^T + softmax over slots; P -> LDS strip ----
  float dacc[4] = {0.f, 0.f, 0.f, 0.f};
#pragma unroll
  for (int t = 0; t < 4; t++) {
    const int nl = wv * 64 + t * 16;
    const int n = n0 + nl + cl;
    f32x4 acc = Z;
#pragma unroll
    for (int ks = 0; ks < 8; ks++) {
      bf16x8 bk = *(const bf16x8*)(fbuf + ((size_t)b * 4096 + n) * 256 + ks * 32 + rq * 8);
      acc = mfma16(aq[ks], bk, acc);
    }
    float l[4];
#pragma unroll
    for (int r = 0; r < 4; r++) l[r] = acc[r] * 0.0625f;
    float m4 = fmaxf(fmaxf(l[0], l[1]), fmaxf(l[2], l[3]));
    float m8 = fmaxf(m4, __shfl_xor(m4, 16, 64));
    float e[4];
    float s4 = 0.f;
#pragma unroll
    for (int r = 0; r < 4; r++) { e[r] = __expf(l[r] - m8); s4 += e[r]; }
    float s8 = s4 + __shfl_xor(s4, 16, 64);
    float inv = 1.f / s8;
    float pa[4];
#pragma unroll
    for (int r = 0; r < 4; r++) pa[r] = e[r] * inv + 1e-8f;
    if (lane < 32) {
#pragma unroll
      for (int r = 0; r < 4; r++) pt[(rq * 4 + r) * 264 + nl + cl] = f2bf(pa[r]);
    }
    if (store_attn && lane < 32) {
#pragma unroll
      for (int r = 0; r < 4; r++)
        attn_out[((size_t)b * 8 + rq * 4 + r) * 4096 + n0 + nl + cl] = pa[r];
    }
#pragma unroll
    for (int r = 0; r < 4; r++) dacc[r] += sum16(pa[r]);
  }
  if (cl == 0 && lane < 32) {
#pragma unroll
    for (int r = 0; r < 4; r++)
      part_den[(((size_t)b * 16 + sub) * 4 + wv) * 8 + rq * 4 + r] = dacc[r];
  }
  __syncthreads();

  // ---- PV: outT[d][s] += fbuf_t[d][n-frag] * P[s][n-frag] ----
  f32x4 acc2[4] = {Z, Z, Z, Z};
#pragma unroll
  for (int ks = 0; ks < 8; ks++) {
    const int noff = ks * 32 + rq * 8;
    bf16x8 bp = *(const bf16x8*)&pt[(cl & 7) * 264 + noff];
#pragma unroll
    for (int dt = 0; dt < 4; dt++) {
      const int d = wv * 64 + dt * 16 + cl;
      bf16x8 af = *(const bf16x8*)(fbuf_t + ((size_t)b * 256 + d) * 4096 + n0 + noff);
      acc2[dt] = mfma16(af, bp, acc2[dt]);
    }
  }
  // lane holds outT[d = wv*64 + dt*16 + rq*4 + r][s = cl]; keep s < 8
  if (cl < 8) {
#pragma unroll
    for (int dt = 0; dt < 4; dt++)
#pragma unroll
      for (int r = 0; r < 4; r++)
        outp[cl * 260 + wv * 64 + dt * 16 + rq * 4 + r] = acc2[dt][r];
  }
  __syncthreads();

  // coalesced partial store
#pragma unroll
  for (int i = 0; i < 8; i++)
    part_acc[(((size_t)b * 16 + sub) * 8 + i) * 256 + tid] = outp[i * 260 + tid];
}

// ---------------------------------------------------------------------------
// U: reduce partials -> Pf_norm; updates = Pf_norm @ Wv^T; GRU; LN; MLP; res.
// (round-3 body, proven)
// ---------------------------------------------------------------------------
__global__ void __launch_bounds__(256) slot_update(
    const float* __restrict__ part_acc, const float* __restrict__ part_den,
    float* __restrict__ slots,
    const u16* __restrict__ wihb, const u16* __restrict__ whhb,
    const float* __restrict__ b_ih, const float* __restrict__ b_hh,
    const float* __restrict__ gm, const float* __restrict__ bm,
    const u16* __restrict__ w1b, const float* __restrict__ b1,
    const u16* __restrict__ w2b, const float* __restrict__ b2,
    const u16* __restrict__ wvb,
    float* __restrict__ slots_out, int last) {
  __shared__ u16 ubf[16 * 264];
  __shared__ u16 hbf[16 * 264];
  __shared__ u16 updbf[16 * 264];
  __shared__ float hf32[8 * 256];
  __shared__ float midf[8 * 256];
  __shared__ u16 h1bf[16 * 1032];
  __shared__ float denl[8];
  const int b = blockIdx.x;
  const int tid = threadIdx.x;
  const int lane = tid & 63;
  const int wv = tid >> 6;
  const int cl = lane & 15;
  const int rq = lane >> 4;
  const f32x4 Z = {0.f, 0.f, 0.f, 0.f};

  for (int i = tid; i < 8 * 264; i += 256) { ubf[8 * 264 + i] = 0; hbf[8 * 264 + i] = 0; }
  if (tid < 8) {
    float s = 0.f;
    for (int c = 0; c < 64; c++) s += part_den[((size_t)b * 64 + c) * 8 + tid];
    denl[tid] = s;
  }
  __syncthreads();

#pragma unroll
  for (int i = 0; i < 8; i++) {
    float s = 0.f;
#pragma unroll
    for (int c = 0; c < 16; c++)
      s += part_acc[(((size_t)b * 16 + c) * 8 + i) * 256 + tid];
    float u = s / denl[i];
    ubf[i * 264 + tid] = f2bf(u);          // Pf_norm (attn_wm @ f_ln)
    float h = slots[((size_t)b * 8 + i) * 256 + tid];
    hf32[i * 256 + tid] = h;
    hbf[i * 264 + tid] = f2bf(h);
  }
  __syncthreads();

  // ---- updates = Pf_norm @ Wv^T -> updbf ----
  {
    bf16x8 apf[8];
#pragma unroll
    for (int ks = 0; ks < 8; ks++)
      apf[ks] = *(const bf16x8*)&ubf[cl * 264 + ks * 32 + rq * 8];
#pragma unroll
    for (int t = 0; t < 4; t++) {
      const int of = wv * 64 + t * 16;
      f32x4 acc = Z;
#pragma unroll
      for (int ks = 0; ks < 8; ks++) {
        bf16x8 bw = *(const bf16x8*)(wvb + (size_t)(of + cl) * 256 + ks * 32 + rq * 8);
        acc = mfma16(apf[ks], bw, acc);
      }
#pragma unroll
      for (int r = 0; r < 4; r++)
        updbf[(rq * 4 + r) * 264 + of + cl] = f2bf(acc[r]);
    }
  }
  __syncthreads();

  // ---- GRU ----
  bf16x8 au[8], ah[8];
#pragma unroll
  for (int ks = 0; ks < 8; ks++) {
    au[ks] = *(const bf16x8*)&updbf[cl * 264 + ks * 32 + rq * 8];
    ah[ks] = *(const bf16x8*)&hbf[cl * 264 + ks * 32 + rq * 8];
  }
#pragma unroll
  for (int j4 = 0; j4 < 4; j4++) {
    const int j = wv * 4 + j4;  // o-tile 0..15
    f32x4 a_ir = Z, a_iz = Z, a_in = Z, a_hr = Z, a_hz = Z, a_hn = Z;
#pragma unroll
    for (int ks = 0; ks < 8; ks++) {
      const int koff = ks * 32 + rq * 8;
      const int o_r = j * 16 + cl;
      bf16x8 bri = *(const bf16x8*)(wihb + (size_t)o_r * 256 + koff);
      bf16x8 bzi = *(const bf16x8*)(wihb + (size_t)(256 + o_r) * 256 + koff);
      bf16x8 bni = *(const bf16x8*)(wihb + (size_t)(512 + o_r) * 256 + koff);
      bf16x8 brh = *(const bf16x8*)(whhb + (size_t)o_r * 256 + koff);
      bf16x8 bzh = *(const bf16x8*)(whhb + (size_t)(256 + o_r) * 256 + koff);
      bf16x8 bnh = *(const bf16x8*)(whhb + (size_t)(512 + o_r) * 256 + koff);
      a_ir = mfma16(au[ks], bri, a_ir);
      a_iz = mfma16(au[ks], bzi, a_iz);
      a_in = mfma16(au[ks], bni, a_in);
      a_hr = mfma16(ah[ks], brh, a_hr);
      a_hz = mfma16(ah[ks], bzh, a_hz);
      a_hn = mfma16(ah[ks], bnh, a_hn);
    }
    if (lane < 32) {
      const int d = j * 16 + cl;
      const float bihr = b_ih[d], bihz = b_ih[256 + d], bihn = b_ih[512 + d];
      const float bhhr = b_hh[d], bhhz = b_hh[256 + d], bhhn = b_hh[512 + d];
#pragma unroll
      for (int r = 0; r < 4; r++) {
        const int s = rq * 4 + r;
        float ir = a_ir[r] + bihr, iz = a_iz[r] + bihz, inn = a_in[r] + bihn;
        float hr = a_hr[r] + bhhr, hz = a_hz[r] + bhhz, hn = a_hn[r] + bhhn;
        float rg = 1.f / (1.f + __expf(-(ir + hr)));
        float zg = 1.f / (1.f + __expf(-(iz + hz)));
        float ng = tanhf(inn + rg * hn);
        float h = hf32[s * 256 + d];
        midf[s * 256 + d] = (1.f - zg) * ng + zg * h;
      }
    }
  }
  __syncthreads();

  // ---- LN (g_mlp,b_mlp) of midf -> ubf (rows 8-15 still zero) ----
  for (int rr = 0; rr < 2; rr++) {
    const int s = wv * 2 + rr;
    float4 x4 = *(const float4*)&midf[s * 256 + lane * 4];
    float x[4] = {x4.x, x4.y, x4.z, x4.w};
    float s1 = x[0] + x[1] + x[2] + x[3];
    float s2 = x[0] * x[0] + x[1] * x[1] + x[2] * x[2] + x[3] * x[3];
    s1 = wave_sum(s1);
    s2 = wave_sum(s2);
    float mu = s1 * (1.f / 256.f);
    float rstd = rsqrtf(s2 * (1.f / 256.f) - mu * mu + 1e-5f);
    float4 g4 = *(const float4*)(gm + lane * 4);
    float4 b4 = *(const float4*)(bm + lane * 4);
    u16 o4[4];
    o4[0] = f2bf((x[0] - mu) * rstd * g4.x + b4.x);
    o4[1] = f2bf((x[1] - mu) * rstd * g4.y + b4.y);
    o4[2] = f2bf((x[2] - mu) * rstd * g4.z + b4.z);
    o4[3] = f2bf((x[3] - mu) * rstd * g4.w + b4.w);
    *(ushort4*)&ubf[s * 264 + lane * 4] = make_ushort4(o4[0], o4[1], o4[2], o4[3]);
  }
  __syncthreads();

  // ---- MLP1: relu(ln @ W1^T + b1) -> h1bf ----
  bf16x8 al[8];
#pragma unroll
  for (int ks = 0; ks < 8; ks++)
    al[ks] = *(const bf16x8*)&ubf[cl * 264 + ks * 32 + rq * 8];
#pragma unroll
  for (int t = 0; t < 16; t++) {
    const int of = wv * 256 + t * 16;
    f32x4 acc = Z;
#pragma unroll
    for (int ks = 0; ks < 8; ks++) {
      bf16x8 bw = *(const bf16x8*)(w1b + (size_t)(of + cl) * 256 + ks * 32 + rq * 8);
      acc = mfma16(al[ks], bw, acc);
    }
    const float bb = b1[of + cl];
#pragma unroll
    for (int r = 0; r < 4; r++)
      h1bf[(rq * 4 + r) * 1032 + of + cl] = f2bf(fmaxf(acc[r] + bb, 0.f));
  }
  __syncthreads();

  // ---- MLP2: mid + h1 @ W2^T + b2 -> slots (and out on last iter) ----
  f32x4 acc2[4] = {Z, Z, Z, Z};
  for (int ks = 0; ks < 32; ks++) {
    bf16x8 ah1 = *(const bf16x8*)&h1bf[cl * 1032 + ks * 32 + rq * 8];
#pragma unroll
    for (int t = 0; t < 4; t++) {
      const int o = wv * 64 + t * 16 + cl;
      bf16x8 bw = *(const bf16x8*)(w2b + (size_t)o * 1024 + ks * 32 + rq * 8);
      acc2[t] = mfma16(ah1, bw, acc2[t]);
    }
  }
  if (lane < 32) {
#pragma unroll
    for (int t = 0; t < 4; t++) {
      const int o = wv * 64 + t * 16 + cl;
      const float bb = b2[o];
#pragma unroll
      for (int r = 0; r < 4; r++) {
        const int s = rq * 4 + r;
        float val = midf[s * 256 + o] + acc2[t][r] + bb;
        slots[((size_t)b * 8 + s) * 256 + o] = val;
        if (last) slots_out[((size_t)b * 8 + s) * 256 + o] = val;
      }
    }
  }
}

// ---------------------------------------------------------------------------
extern "C" void kernel_launch(void* const* d_in, const int* in_sizes, int n_in,
                              void* d_out, int out_size, void* d_ws, size_t ws_size,
                              hipStream_t stream) {
  (void)in_sizes; (void)n_in; (void)out_size;
  const float* features = (const float*)d_in[0];
  const float* slots_init = (const float*)d_in[1];
  const float* g_feat = (const float*)d_in[2];
  const float* b_feat = (const float*)d_in[3];
  const float* g_slots = (const float*)d_in[4];
  const float* b_slots = (const float*)d_in[5];
  const float* g_mlp = (const float*)d_in[6];
  const float* b_mlp = (const float*)d_in[7];
  const float* Wk = (const float*)d_in[8];
  const float* Wv = (const float*)d_in[9];
  const float* Wq = (const float*)d_in[10];
  const float* w_ih = (const float*)d_in[11];
  const float* w_hh = (const float*)d_in[12];
  const float* b_ih = (const float*)d_in[13];
  const float* b_hh = (const float*)d_in[14];
  const float* W1 = (const float*)d_in[15];
  const float* b1 = (const float*)d_in[16];
  const float* W2 = (const float*)d_in[17];
  const float* b2 = (const float*)d_in[18];

  // Workspace layout (bytes). Total = 280,236,032.
  const size_t REQUIRED = 280236032ull;
  if (ws_size < REQUIRED) return;

  char* ws = (char*)d_ws;
  u16* fbuf = (u16*)(ws + 0);                  // 134,217,728  LN(feat) [b][n][d]
  u16* fbuf_t = (u16*)(ws + 134217728);        // 134,217,728  LN(feat) [b][d][n]
  u16* qkbuf = (u16*)(ws + 268435456);         // 524,288      [b][16][256]
  float* part_acc = (float*)(ws + 268959744);  // 8,388,608    [b][16][8][256]
  float* part_den = (float*)(ws + 277348352);  // 131,072      [b][16][4][8]
  float* slots = (float*)(ws + 277479424);     // 524,288
  u16* wktb = (u16*)(ws + 278003712);          // 131,072  Wk^T bf16
  u16* wvb = (u16*)(ws + 278134784);           // 131,072  Wv bf16
  u16* wqb = (u16*)(ws + 278269952);           // 131,072
  u16* wihb = (u16*)(ws + 278401024);          // 393,216
  u16* whhb = (u16*)(ws + 278794240);          // 393,216
  u16* w1b = (u16*)(ws + 279187456);           // 524,288
  u16* w2b = (u16*)(ws + 279711744);           // 524,288

  float* out_slots = (float*)d_out;
  float* out_attn = out_slots + 131072;

  init_prep<<<1168, 256, 0, stream>>>(Wk, Wv, slots_init, Wq, w_ih, w_hh, W1, W2,
                                      slots, wqb, wihb, whhb, w1b, w2b, wvb, wktb);
  ln_feat<<<4096, 256, 0, stream>>>(features, g_feat, b_feat, fbuf, fbuf_t);
  for (int it = 0; it < 3; it++) {
    slot_qk<<<64, 256, 0, stream>>>(slots, g_slots, b_slots, wqb, wktb, qkbuf);
    attn_pass<<<dim3(16, 64), 256, 0, stream>>>(qkbuf, fbuf, fbuf_t, part_acc, part_den,
                                                out_attn, it == 2 ? 1 : 0);
    slot_update<<<64, 256, 0, stream>>>(part_acc, part_den, slots, wihb, whhb, b_ih, b_hh,
                                        g_mlp, b_mlp, w1b, b1, w2b, b2, wvb,
                                        out_slots, it == 2 ? 1 : 0);
  }
}